// Round 21
// baseline (301.812 us; speedup 1.0000x reference)
//
#include <hip/hip_runtime.h>
#include <hip/hip_bf16.h>

#define B_ 2
#define C_ 256
#define H_ 128
#define W_ 128
#define HW_ 16384
#define QK_ 256
#define HEADS_ 8
#define HD_ 32
#define TOPK_ 128
#define NSP_ 256
#define SCALE_F 0.17677669529663687f
#define SC2_F 0.25500299976f        // SCALE_F * log2(e)
#define EPS_ 1e-6f

typedef __attribute__((ext_vector_type(16))) float f32x16;
typedef __attribute__((ext_vector_type(8))) short bf16x8;
typedef unsigned short ushort_t;
union FragU { unsigned int u[4]; bf16x8 v; };

// manual f32 -> bf16 (round-to-nearest-even), pure VALU, no asm (fallback tiers)
__device__ __forceinline__ ushort_t f2bf(float x)
{
    unsigned u = __float_as_uint(x);
    return (ushort_t)((u + 0x7fffu + ((u >> 16) & 1u)) >> 16);
}
__device__ __forceinline__ float bf2f(ushort_t h)
{
    return __uint_as_float((unsigned)h << 16);
}
__device__ __forceinline__ unsigned pk2(float a, float b)
{
    return (unsigned)f2bf(a) | ((unsigned)f2bf(b) << 16);
}

// native pair conversion: compiler emits v_cvt_pk_bf16_f32 (RNE), AGPR-safe
__device__ __forceinline__ unsigned pk2n(float a, float b)
{
    __hip_bfloat162 h2 = __float22bfloat162_rn(make_float2(a, b));
    union { __hip_bfloat162 h; unsigned u; } c;
    c.h = h2;
    return c.u;
}

// cross-half exchange: o0 = hi ? partner(b) : a ; o1 = hi ? b : partner(a)
__device__ __forceinline__ void half_swap(unsigned a, unsigned b,
                                          unsigned& o0, unsigned& o1, int hi)
{
#if __has_builtin(__builtin_amdgcn_permlane32_swap)
    auto r = __builtin_amdgcn_permlane32_swap(a, b, false, false);
    o0 = (unsigned)r[0];
    o1 = (unsigned)r[1];
#else
    unsigned sa = (unsigned)__shfl_xor((int)a, 32);
    unsigned sb = (unsigned)__shfl_xor((int)b, 32);
    o0 = hi ? sb : a;
    o1 = hi ? b : sa;
#endif
}

// fragment-linear layout: frag[panel][ks][lane] of bf16x8 (16B each)
__device__ __forceinline__ size_t frag_off(int panel, int ks, int lane)
{
    return (((size_t)panel * 16 + ks) * 64 + lane) * 8;
}

// split 8 f32 into bf16 hi + bf16 residual fragments (fp32-emulation, fallback tiers)
__device__ __forceinline__ void split8(const float* f, FragU& hi, FragU& lo)
{
    #pragma unroll
    for (int j = 0; j < 4; j++) {
        ushort_t h0 = f2bf(f[2*j]);
        ushort_t h1 = f2bf(f[2*j+1]);
        hi.u[j] = (unsigned)h0 | ((unsigned)h1 << 16);
        lo.u[j] = pk2(f[2*j] - bf2f(h0), f[2*j+1] - bf2f(h1));
    }
}

// ---------------- mean / rstd per pixel (fallback tiers only) ----------------
__global__ __launch_bounds__(256) void k_meanvar(const float* __restrict__ x, float* __restrict__ mu_rstd)
{
    int p = blockIdx.x * 256 + threadIdx.x;
    int b = p >> 14, pp = p & (HW_ - 1);
    const float* xb = x + (size_t)b * C_ * HW_ + pp;
    float s = 0.f, s2 = 0.f;
    for (int c = 0; c < C_; c++) {
        float v = xb[(size_t)c * HW_];
        s += v; s2 += v * v;
    }
    float mu = s * (1.f / C_);
    float var = s2 * (1.f / C_) - mu * mu;
    float rstd = rsqrtf(var + EPS_);
    mu_rstd[2 * p] = mu;
    mu_rstd[2 * p + 1] = rstd;
}

// ---------------- weight -> bf16 fragment layout: wf[panel(24)][ks][lane] ----------------
__global__ __launch_bounds__(256) void k_wsplit16(
    const float* __restrict__ wq, const float* __restrict__ wk, const float* __restrict__ wv,
    ushort_t* __restrict__ wf)
{
    const int panel = blockIdx.x;                 // 0..23
    const int lm = threadIdx.x & 31;
    const int kg = threadIdx.x >> 5;
    const int k0 = kg * 32;
    const int n = panel * 32 + lm;
    const float* wr = (n < 256) ? (wq + (size_t)n * C_)
                   : (n < 512) ? (wk + (size_t)(n - 256) * C_)
                               : (wv + (size_t)(n - 512) * C_);
    float v[32];
    #pragma unroll
    for (int j4 = 0; j4 < 8; j4++) {
        float4 t = *(const float4*)(wr + k0 + j4 * 4);
        v[j4*4+0] = t.x; v[j4*4+1] = t.y; v[j4*4+2] = t.z; v[j4*4+3] = t.w;
    }
    uint4 hv[4];
    unsigned* hp = (unsigned*)hv;
    #pragma unroll
    for (int jp = 0; jp < 16; jp++)
        hp[jp] = pk2n(v[2*jp], v[2*jp+1]);
    #pragma unroll
    for (int q = 0; q < 4; q++) {
        const int kk = k0 + 8 * q;
        const int ks = kk >> 4;
        const int hi = (kk >> 3) & 1;
        *(uint4*)(wf + frag_off(panel, ks, lm + 32 * hi)) = hv[q];
    }
}

// ---------------- fused meanvar + LN -> bf16 fragment layout ----------------
__global__ __launch_bounds__(256) void k_lnsplit16(
    const float* __restrict__ x, const float* __restrict__ gamma, const float* __restrict__ beta,
    ushort_t* __restrict__ xf)
{
    const int b = blockIdx.y;
    const int m0 = blockIdx.x * 32;
    const int lm = threadIdx.x & 31;
    const int kg = threadIdx.x >> 5;
    const int k0 = kg * 32;
    const int m = m0 + lm;
    const float* xb = x + (size_t)b * C_ * HW_ + m;
    __shared__ float g_l[C_], b_l[C_];
    __shared__ float red[2][8][32];
    g_l[threadIdx.x] = gamma[threadIdx.x];
    b_l[threadIdx.x] = beta[threadIdx.x];

    float v[32];
    float s = 0.f, s2 = 0.f;
    #pragma unroll
    for (int j = 0; j < 32; j++) {
        v[j] = xb[(size_t)(k0 + j) * HW_];
        s += v[j]; s2 += v[j] * v[j];
    }
    red[0][kg][lm] = s; red[1][kg][lm] = s2;
    __syncthreads();
    float ts = 0.f, ts2 = 0.f;
    #pragma unroll
    for (int g = 0; g < 8; g++) { ts += red[0][g][lm]; ts2 += red[1][g][lm]; }
    const float mu = ts * (1.f / C_);
    const float var = ts2 * (1.f / C_) - mu * mu;
    const float rstd = rsqrtf(var + EPS_);

    uint4 hv[4];
    unsigned* hp = (unsigned*)hv;
    #pragma unroll
    for (int jp = 0; jp < 16; jp++) {
        float l0 = (v[2*jp]   - mu) * rstd * g_l[k0 + 2*jp]   + b_l[k0 + 2*jp];
        float l1 = (v[2*jp+1] - mu) * rstd * g_l[k0 + 2*jp+1] + b_l[k0 + 2*jp+1];
        hp[jp] = pk2n(l0, l1);
    }
    const int panel = b * (HW_ / 32) + blockIdx.x;
    #pragma unroll
    for (int q = 0; q < 4; q++) {
        const int kk = k0 + 8 * q;
        const int ks = kk >> 4;
        const int hi = (kk >> 3) & 1;
        *(uint4*)(xf + frag_off(panel, ks, lm + 32 * hi)) = hv[q];
    }
}

// ---------------- MFMA QKV GEMM (pure bf16, fragment-linear operands, bf16 out) ----------------
__global__ __launch_bounds__(256) void k_qkv_mfma16(
    const ushort_t* __restrict__ xf, const ushort_t* __restrict__ wf,
    ushort_t* __restrict__ qkv16)
{
    const int b = blockIdx.z;
    const int m0 = blockIdx.x * 128, n0 = blockIdx.y * 128;
    const int tid = threadIdx.x;
    const int lane = tid & 63, wv = tid >> 6;
    const int wr = wv >> 1, wc = wv & 1;
    const int lm = lane & 31;

    const int pa0 = b * (HW_ / 32) + (m0 >> 5) + wr * 2;
    const int pa1 = pa0 + 1;
    const int pb0 = (n0 >> 5) + wc * 2;
    const int pb1 = pb0 + 1;

    f32x16 acc00, acc01, acc10, acc11;
    #pragma unroll
    for (int r = 0; r < 16; r++) { acc00[r] = 0.f; acc01[r] = 0.f; acc10[r] = 0.f; acc11[r] = 0.f; }

    #pragma unroll 8
    for (int ks = 0; ks < 16; ks++) {
        bf16x8 a0 = *(const bf16x8*)(xf + frag_off(pa0, ks, lane));
        bf16x8 a1 = *(const bf16x8*)(xf + frag_off(pa1, ks, lane));
        bf16x8 b0 = *(const bf16x8*)(wf + frag_off(pb0, ks, lane));
        bf16x8 b1 = *(const bf16x8*)(wf + frag_off(pb1, ks, lane));
        acc00 = __builtin_amdgcn_mfma_f32_32x32x16_bf16(b0, a0, acc00, 0, 0, 0);
        acc01 = __builtin_amdgcn_mfma_f32_32x32x16_bf16(b1, a0, acc01, 0, 0, 0);
        acc10 = __builtin_amdgcn_mfma_f32_32x32x16_bf16(b0, a1, acc10, 0, 0, 0);
        acc11 = __builtin_amdgcn_mfma_f32_32x32x16_bf16(b1, a1, acc11, 0, 0, 0);
    }

    const int hv4 = (lane >> 5) * 4;
    #define STORE_ACC(ACC, MT, NT) { \
        ushort_t* o = qkv16 + ((size_t)b * HW_ + m0 + wr * 64 + (MT) * 32 + lm) * 768 \
                    + n0 + wc * 64 + (NT) * 32 + hv4; \
        _Pragma("unroll") \
        for (int g = 0; g < 4; g++) { \
            uint2 pr; \
            pr.x = pk2n(ACC[4*g + 0], ACC[4*g + 1]); \
            pr.y = pk2n(ACC[4*g + 2], ACC[4*g + 3]); \
            *(uint2*)(o + 8 * g) = pr; } }
    STORE_ACC(acc00, 0, 0)
    STORE_ACC(acc01, 0, 1)
    STORE_ACC(acc10, 1, 0)
    STORE_ACC(acc11, 1, 1)
    #undef STORE_ACC
}

// ---------------- fused LN + QKV GEMM (fp32, fallback tiers) ----------------
#define GBM 128
#define GBN 128
#define GBK 8
__global__ __launch_bounds__(256) void k_qkv_gemm(
    const float* __restrict__ x, const float* __restrict__ mu_rstd,
    const float* __restrict__ gamma, const float* __restrict__ beta,
    const float* __restrict__ wq, const float* __restrict__ wk, const float* __restrict__ wv,
    float* __restrict__ qkv)
{
    const int b  = blockIdx.z;
    const int m0 = blockIdx.x * GBM;
    const int n0 = blockIdx.y * GBN;
    __shared__ float a_l[GBK][GBM + 4];
    __shared__ float b_l[GBK][GBN + 4];
    __shared__ float g_l[C_], bt_l[C_];
    const int tid = threadIdx.x;
    g_l[tid] = gamma[tid];
    bt_l[tid] = beta[tid];

    const int mm = tid & 127;
    const int kg = tid >> 7;
    const int nn = tid >> 1;
    const int kq = (tid & 1) * 4;
    const float2 mr = ((const float2*)mu_rstd)[b * HW_ + m0 + mm];
    const float* xbase = x + (size_t)b * C_ * HW_ + m0 + mm;
    const int n = n0 + nn;
    const float* wrow = (n < 256) ? (wq + (size_t)n * C_)
                     : (n < 512) ? (wk + (size_t)(n - 256) * C_)
                                 : (wv + (size_t)(n - 512) * C_);
    float acc[8][8] = {};
    const int tx = tid & 15, ty = tid >> 4;

    for (int kt = 0; kt < C_; kt += GBK) {
        __syncthreads();
        #pragma unroll
        for (int j = 0; j < 4; j++) {
            int kk = kg + j * 2;
            int c = kt + kk;
            float xv = xbase[(size_t)c * HW_];
            a_l[kk][mm] = (xv - mr.x) * mr.y * g_l[c] + bt_l[c];
        }
        float4 w4 = *(const float4*)(wrow + kt + kq);
        b_l[kq + 0][nn] = w4.x; b_l[kq + 1][nn] = w4.y;
        b_l[kq + 2][nn] = w4.z; b_l[kq + 3][nn] = w4.w;
        __syncthreads();
        #pragma unroll
        for (int kk = 0; kk < GBK; kk++) {
            float4 a0 = *(const float4*)&a_l[kk][ty * 8];
            float4 a1 = *(const float4*)&a_l[kk][ty * 8 + 4];
            float4 b0 = *(const float4*)&b_l[kk][tx * 8];
            float4 b1 = *(const float4*)&b_l[kk][tx * 8 + 4];
            float av[8] = {a0.x,a0.y,a0.z,a0.w,a1.x,a1.y,a1.z,a1.w};
            float bv[8] = {b0.x,b0.y,b0.z,b0.w,b1.x,b1.y,b1.z,b1.w};
            #pragma unroll
            for (int i = 0; i < 8; i++)
                #pragma unroll
                for (int jj = 0; jj < 8; jj++)
                    acc[i][jj] += av[i] * bv[jj];
        }
    }
    float* out0 = qkv + ((size_t)b * HW_ + m0 + ty * 8) * 768 + n0 + tx * 8;
    #pragma unroll
    for (int i = 0; i < 8; i++) {
        *(float4*)(out0 + (size_t)i * 768)     = make_float4(acc[i][0], acc[i][1], acc[i][2], acc[i][3]);
        *(float4*)(out0 + (size_t)i * 768 + 4) = make_float4(acc[i][4], acc[i][5], acc[i][6], acc[i][7]);
    }
}

// ---------------- exact top-128: radix-256, 8 waves, bank-staggered histograms ----------------
__device__ __forceinline__ unsigned fkeyu(unsigned u)
{
    return (u & 0x80000000u) ? ~u : (u | 0x80000000u);
}
__device__ __forceinline__ unsigned ifkey(unsigned k)
{
    return (k & 0x80000000u) ? (k ^ 0x80000000u) : ~k;
}

__global__ __launch_bounds__(512) void k_topk(const unsigned* __restrict__ aff,
                                              int* __restrict__ idxo, float* __restrict__ simso)
{
    const int row = blockIdx.x;
    const int tid = threadIdx.x;
    const int lane = tid & 63, wid = tid >> 6;       // 8 waves
    __shared__ __align__(16) unsigned key_l[HW_];    // 64 KB
    __shared__ unsigned hist[8][257];                // stride 257 => same bin spans 8 banks
    __shared__ unsigned sh_prefix;
    __shared__ int sh_need;
    __shared__ int partG[8], partE[8];

    // stage fkeys once (coalesced uint4)
    const uint4* a4 = (const uint4*)(aff + (size_t)row * HW_);
    #pragma unroll 8
    for (int j = 0; j < 8; j++) {
        int i4 = j * 512 + tid;
        uint4 v = a4[i4];
        key_l[4 * i4 + 0] = fkeyu(v.x);
        key_l[4 * i4 + 1] = fkeyu(v.y);
        key_l[4 * i4 + 2] = fkeyu(v.z);
        key_l[4 * i4 + 3] = fkeyu(v.w);
    }
    for (int i = tid; i < 8 * 257; i += 512) ((unsigned*)hist)[i] = 0u;
    if (tid == 0) { sh_prefix = 0u; sh_need = TOPK_; }
    __syncthreads();

    const int qbase = wid * 2048;                    // each wave owns 2048 keys

    // pass-0 histogram (full array, top 8 bits), per-wave sub-histogram
    #pragma unroll 8
    for (int j = 0; j < 8; j++) {
        uint4 k4 = *(const uint4*)&key_l[qbase + j * 256 + lane * 4];
        #pragma unroll
        for (int e = 0; e < 4; e++)
            atomicAdd(&hist[wid][((const unsigned*)&k4)[e] >> 24], 1u);
    }
    __syncthreads();

    for (int pass = 0; pass < 4; pass++) {
        if (wid == 0) {
            const unsigned pref = sh_prefix;
            const unsigned need = (unsigned)sh_need;
            unsigned c[4]; unsigned loc = 0;
            #pragma unroll
            for (int i = 0; i < 4; i++) {
                unsigned t = 0;
                #pragma unroll
                for (int hh = 0; hh < 8; hh++) t += hist[hh][lane*4+i];
                c[i] = t;
                loc += t;
            }
            unsigned s = loc;
            #pragma unroll
            for (int off = 1; off < 64; off <<= 1) {
                unsigned t = (unsigned)__shfl_down((int)s, off);
                if (lane + off < 64) s += t;
            }
            unsigned run = s - loc;
            #pragma unroll
            for (int i = 3; i >= 0; i--) {
                unsigned incl = run + c[i];
                if (incl >= need && run < need) {
                    sh_prefix = (pref << 8) | (unsigned)(lane * 4 + i);
                    sh_need = (int)(need - run);
                }
                run = incl;
            }
        }
        __syncthreads();
        if (pass == 3) break;

        const unsigned prefT = sh_prefix;
        const int shift = 24 - 8 * pass;
        for (int i = tid; i < 8 * 257; i += 512) ((unsigned*)hist)[i] = 0u;
        __syncthreads();
        const int nshift = shift - 8;
        #pragma unroll 8
        for (int j = 0; j < 8; j++) {
            uint4 k4 = *(const uint4*)&key_l[qbase + j * 256 + lane * 4];
            #pragma unroll
            for (int e = 0; e < 4; e++) {
                unsigned key = ((const unsigned*)&k4)[e];
                if ((key >> shift) == prefT)
                    atomicAdd(&hist[wid][(key >> nshift) & 255u], 1u);
            }
        }
        __syncthreads();
    }

    const unsigned T = sh_prefix;
    const int e_take = sh_need;

    int cg = 0, ce = 0;
    #pragma unroll 8
    for (int j = 0; j < 8; j++) {
        uint4 k4 = *(const uint4*)&key_l[qbase + j * 256 + lane * 4];
        #pragma unroll
        for (int e = 0; e < 4; e++) {
            unsigned key = ((const unsigned*)&k4)[e];
            cg += (key > T);
            ce += (key == T);
        }
    }
    #pragma unroll
    for (int o = 32; o >= 1; o >>= 1) { cg += __shfl_xor(cg, o); ce += __shfl_xor(ce, o); }
    if (lane == 0) { partG[wid] = cg; partE[wid] = ce; }
    __syncthreads();

    int gpre = 0, epre = 0;
    for (int q = 0; q < wid; q++) { gpre += partG[q]; epre += partE[q]; }
    int base = gpre + ((epre < e_take) ? epre : e_take);
    int rem_eq = e_take - epre;
    if (rem_eq < 0) rem_eq = 0;
    if (rem_eq > ce) rem_eq = ce;

    int* orow = idxo + (size_t)row * TOPK_;
    float* srow = simso + (size_t)row * TOPK_;
    const unsigned long long ltm = (1ULL << lane) - 1ULL;

    for (int j = 0; j < 32; j++) {
        const int i = qbase + j * 64 + lane;
        const unsigned key = key_l[i];
        const bool gt = key > T;
        const bool eq = (key == T);
        const unsigned long long bg = __ballot(gt);
        const unsigned long long be = __ballot(eq);
        const int cgc = __popcll(bg);
        const int cec = __popcll(be);
        if (gt) {
            int slot = base + __popcll(bg & ltm);
            orow[slot] = i; srow[slot] = __uint_as_float(ifkey(key));
        }
        if (eq && rem_eq > 0) {
            int r = __popcll(be & ltm);
            if (r < rem_eq) {
                int slot = base + cgc + r;
                orow[slot] = i; srow[slot] = __uint_as_float(ifkey(key));
            }
        }
        const int etk = (cec < rem_eq) ? cec : rem_eq;
        base += cgc + etk;
        rem_eq -= etk;
    }
}

// ---------------- CSR inverse-index construction ----------------
__global__ __launch_bounds__(128) void k_count(const int* __restrict__ idxb, int* __restrict__ cnt)
{
    const int sp = blockIdx.x, b = blockIdx.y;
    int pix = idxb[(b * NSP_ + sp) * TOPK_ + threadIdx.x];
    atomicAdd(&cnt[b * HW_ + pix], 1);
}

__global__ __launch_bounds__(1024) void k_scan(const int* __restrict__ cnt, int* __restrict__ offs)
{
    const int b = blockIdx.x;
    const int tid = threadIdx.x;
    __shared__ int sc[1024];
    const int base = b * HW_;
    int loc[16];
    int s = 0;
    #pragma unroll
    for (int i = 0; i < 16; i++) {
        int c = cnt[base + tid * 16 + i];
        loc[i] = s;
        s += c;
    }
    sc[tid] = s;
    __syncthreads();
    for (int off = 1; off < 1024; off <<= 1) {
        int add = (tid >= off) ? sc[tid - off] : 0;
        __syncthreads();
        sc[tid] += add;
        __syncthreads();
    }
    int excl = sc[tid] - s;
    #pragma unroll
    for (int i = 0; i < 16; i++)
        offs[base + tid * 16 + i] = excl + loc[i];
}

// fill: compute each slot's DESTINATION position in CSR order (dpos), global row id
__global__ __launch_bounds__(128) void k_fill(const int* __restrict__ idxb, const int* __restrict__ offs,
                                              int* __restrict__ cursor, int* __restrict__ dpos)
{
    const int sp = blockIdx.x, b = blockIdx.y;
    const int slot = threadIdx.x;
    const int gid = (b * NSP_ + sp) * TOPK_ + slot;
    int pix = idxb[gid];
    int pos = atomicAdd(&cursor[b * HW_ + pix], 1);
    dpos[gid] = b * (NSP_ * TOPK_) + offs[b * HW_ + pix] + pos;
}

// ---------------- MFMA attention, bf16 qkv (tier 1) ----------------
__global__ __launch_bounds__(256, 8) void k_attn16(
    const ushort_t* __restrict__ qkv16, const int* __restrict__ idxb,
    const int* __restrict__ dpos, const float* __restrict__ sims,
    ushort_t* __restrict__ O16)
{
    const int sp = blockIdx.x, h = blockIdx.y, b = blockIdx.z;
    __shared__ int idx_l[TOPK_];
    __shared__ int dp_l[TOPK_];
    __shared__ float sims_l[TOPK_];
    __shared__ __align__(16) ushort_t vt[HD_][TOPK_ + 8];

    const int tid = threadIdx.x;
    const int roff = (b * NSP_ + sp) * TOPK_;
    if (tid < TOPK_) {
        idx_l[tid] = idxb[roff + tid];
        dp_l[tid] = dpos[roff + tid];
        sims_l[tid] = sims[roff + tid];
    }
    __syncthreads();

    const ushort_t* qb = qkv16 + (size_t)b * HW_ * 768;

    // stage sims-weighted V^T into LDS (bf16, native pair converts)
    {
        const int s = tid >> 1, ch = (tid & 1) * 16;
        const float wgt = sims_l[s];
        const ushort_t* vrow = qb + (size_t)idx_l[s] * 768 + 512 + h * HD_ + ch;
        bf16x8 v0 = *(const bf16x8*)(vrow);
        bf16x8 v1 = *(const bf16x8*)(vrow + 8);
        #pragma unroll
        for (int jp = 0; jp < 4; jp++) {
            unsigned p0 = pk2n(bf2f((ushort_t)v0[2*jp]) * wgt, bf2f((ushort_t)v0[2*jp+1]) * wgt);
            vt[ch + 2*jp][s]     = (ushort_t)p0;
            vt[ch + 2*jp + 1][s] = (ushort_t)(p0 >> 16);
            unsigned p1 = pk2n(bf2f((ushort_t)v1[2*jp]) * wgt, bf2f((ushort_t)v1[2*jp+1]) * wgt);
            vt[ch + 8 + 2*jp][s]     = (ushort_t)p1;
            vt[ch + 8 + 2*jp + 1][s] = (ushort_t)(p1 >> 16);
        }
    }

    const int lane = tid & 63, w = tid >> 6;
    const int lq = lane & 31, hi = lane >> 5;
    const int qrow = idx_l[w * 32 + lq];

    f32x16 sacc[4];
    #pragma unroll
    for (int s = 0; s < 4; s++)
        #pragma unroll
        for (int r = 0; r < 16; r++) sacc[s][r] = 0.f;

    // QK^T: direct bf16 fragments (A = K rows, B = Q^T cols)
    #pragma unroll
    for (int t = 0; t < 2; t++) {
        bf16x8 qf = *(const bf16x8*)(qb + (size_t)qrow * 768 + h * HD_ + t * 16 + hi * 8);
        #pragma unroll
        for (int s = 0; s < 4; s++) {
            const int krow = idx_l[s * 32 + lq];
            bf16x8 kf = *(const bf16x8*)(qb + (size_t)krow * 768 + 256 + h * HD_ + t * 16 + hi * 8);
            sacc[s] = __builtin_amdgcn_mfma_f32_32x32x16_bf16(kf, qf, sacc[s], 0, 0, 0);
        }
    }

    // full softmax over s (lane holds 64 of 128; partner in lane^32)
    // max via v_max3-shaped pairs
    float m = fmaxf(sacc[0][0], sacc[0][1]);
    #pragma unroll
    for (int s = 0; s < 4; s++)
        #pragma unroll
        for (int r = (s == 0 ? 2 : 0); r < 16; r += 2)
            m = fmaxf(m, fmaxf(sacc[s][r], sacc[s][r + 1]));
    m = fmaxf(m, __shfl_xor(m, 32));
    const float mb = -m * SC2_F;                    // exp2 prescale
    float l0 = 0.f, l1 = 0.f;
    #pragma unroll
    for (int s = 0; s < 4; s++)
        #pragma unroll
        for (int r = 0; r < 16; r += 2) {
            float p0 = exp2f(fmaf(sacc[s][r],     SC2_F, mb));
            float p1 = exp2f(fmaf(sacc[s][r + 1], SC2_F, mb));
            sacc[s][r] = p0;
            sacc[s][r + 1] = p1;
            l0 += p0;
            l1 += p1;
        }
    float lsum = l0 + l1;
    lsum += __shfl_xor(lsum, 32);

    __syncthreads();   // vt ready

    f32x16 oacc;
    #pragma unroll
    for (int r = 0; r < 16; r++) oacc[r] = 0.f;

    #pragma unroll
    for (int t = 0; t < 8; t++) {
        const int st = t >> 1, rb = (t & 1) * 8;
        unsigned A0 = pk2n(sacc[st][rb + 0], sacc[st][rb + 1]);
        unsigned A1 = pk2n(sacc[st][rb + 2], sacc[st][rb + 3]);
        unsigned B0 = pk2n(sacc[st][rb + 4], sacc[st][rb + 5]);
        unsigned B1 = pk2n(sacc[st][rb + 6], sacc[st][rb + 7]);
        FragU pf;
        half_swap(A0, B0, pf.u[0], pf.u[2], hi);
        half_swap(A1, B1, pf.u[1], pf.u[3], hi);
        bf16x8 vf = *(const bf16x8*)&vt[lq][t * 16 + hi * 8];
        oacc = __builtin_amdgcn_mfma_f32_32x32x16_bf16(vf, pf.v, oacc, 0, 0, 0);
    }

    const float wt = sims_l[w * 32 + lq] / lsum;
    ushort_t* orow = O16 + (size_t)dp_l[w * 32 + lq] * C_ + h * HD_ + 4 * hi;
    #pragma unroll
    for (int g = 0; g < 4; g++) {
        uint2 pr;
        pr.x = pk2n(oacc[4*g + 0] * wt, oacc[4*g + 1] * wt);
        pr.y = pk2n(oacc[4*g + 2] * wt, oacc[4*g + 3] * wt);
        *(uint2*)(orow + 8 * g) = pr;
    }
}

// ---------------- MFMA attention, fp32 qkv (fallback tiers) ----------------
template <bool DENSE>
__global__ __launch_bounds__(256) void k_attn_mfma(
    const float* __restrict__ qkv, const int* __restrict__ idxb,
    const int* __restrict__ dpos, const float* __restrict__ sims,
    ushort_t* __restrict__ O16, float* __restrict__ tmp)
{
    const int sp = blockIdx.x, h = blockIdx.y, b = blockIdx.z;
    __shared__ int idx_l[TOPK_];
    __shared__ int dp_l[TOPK_];
    __shared__ float sims_l[TOPK_];
    __shared__ __align__(16) ushort_t vt[HD_][TOPK_ + 8];

    const int tid = threadIdx.x;
    const int roff = (b * NSP_ + sp) * TOPK_;
    if (tid < TOPK_) {
        idx_l[tid] = idxb[roff + tid];
        sims_l[tid] = sims[roff + tid];
        if (DENSE) dp_l[tid] = dpos[roff + tid];
    }
    __syncthreads();

    const float* qb = qkv + (size_t)b * HW_ * 768;

    {
        const int s = tid >> 1, ch = (tid & 1) * 16;
        const float wgt = sims_l[s];
        const float* vrow = qb + (size_t)idx_l[s] * 768 + 512 + h * HD_ + ch;
        #pragma unroll
        for (int j4 = 0; j4 < 4; j4++) {
            float4 vv = *(const float4*)(vrow + j4 * 4);
            vt[ch + j4 * 4 + 0][s] = f2bf(vv.x * wgt);
            vt[ch + j4 * 4 + 1][s] = f2bf(vv.y * wgt);
            vt[ch + j4 * 4 + 2][s] = f2bf(vv.z * wgt);
            vt[ch + j4 * 4 + 3][s] = f2bf(vv.w * wgt);
        }
    }

    const int lane = tid & 63, w = tid >> 6;
    const int lq = lane & 31, hi = lane >> 5;
    const int qrow = idx_l[w * 32 + lq];

    f32x16 sacc[4];
    #pragma unroll
    for (int s = 0; s < 4; s++)
        #pragma unroll
        for (int r = 0; r < 16; r++) sacc[s][r] = 0.f;

    #pragma unroll
    for (int t = 0; t < 2; t++) {
        const float* qp = qb + (size_t)qrow * 768 + h * HD_ + t * 16 + hi * 8;
        float q8[8];
        {
            float4 t0 = *(const float4*)qp;
            float4 t1 = *(const float4*)(qp + 4);
            q8[0]=t0.x; q8[1]=t0.y; q8[2]=t0.z; q8[3]=t0.w;
            q8[4]=t1.x; q8[5]=t1.y; q8[6]=t1.z; q8[7]=t1.w;
        }
        FragU qh, ql; split8(q8, qh, ql);
        #pragma unroll
        for (int s = 0; s < 4; s++) {
            const int krow = idx_l[s * 32 + lq];
            const float* kp = qb + (size_t)krow * 768 + 256 + h * HD_ + t * 16 + hi * 8;
            float k8[8];
            {
                float4 t0 = *(const float4*)kp;
                float4 t1 = *(const float4*)(kp + 4);
                k8[0]=t0.x; k8[1]=t0.y; k8[2]=t0.z; k8[3]=t0.w;
                k8[4]=t1.x; k8[5]=t1.y; k8[6]=t1.z; k8[7]=t1.w;
            }
            FragU kh, kl; split8(k8, kh, kl);
            sacc[s] = __builtin_amdgcn_mfma_f32_32x32x16_bf16(kh.v, qh.v, sacc[s], 0, 0, 0);
            sacc[s] = __builtin_amdgcn_mfma_f32_32x32x16_bf16(kh.v, ql.v, sacc[s], 0, 0, 0);
            sacc[s] = __builtin_amdgcn_mfma_f32_32x32x16_bf16(kl.v, qh.v, sacc[s], 0, 0, 0);
        }
    }

    float m = -1e30f;
    #pragma unroll
    for (int s = 0; s < 4; s++)
        #pragma unroll
        for (int r = 0; r < 16; r++) m = fmaxf(m, sacc[s][r]);
    m = fmaxf(m, __shfl_xor(m, 32));
    float lsum = 0.f;
    #pragma unroll
    for (int s = 0; s < 4; s++)
        #pragma unroll
        for (int r = 0; r < 16; r++) {
            float p = __expf((sacc[s][r] - m) * SCALE_F);
            sacc[s][r] = p;
            lsum += p;
        }
    lsum += __shfl_xor(lsum, 32);

    __syncthreads();

    f32x16 oacc;
    #pragma unroll
    for (int r = 0; r < 16; r++) oacc[r] = 0.f;

    #pragma unroll
    for (int t = 0; t < 8; t++) {
        const int st = t >> 1, rb = (t & 1) * 8;
        unsigned A0 = pk2(sacc[st][rb + 0], sacc[st][rb + 1]);
        unsigned A1 = pk2(sacc[st][rb + 2], sacc[st][rb + 3]);
        unsigned B0 = pk2(sacc[st][rb + 4], sacc[st][rb + 5]);
        unsigned B1 = pk2(sacc[st][rb + 6], sacc[st][rb + 7]);
        unsigned sA0 = (unsigned)__shfl_xor((int)A0, 32);
        unsigned sA1 = (unsigned)__shfl_xor((int)A1, 32);
        unsigned sB0 = (unsigned)__shfl_xor((int)B0, 32);
        unsigned sB1 = (unsigned)__shfl_xor((int)B1, 32);
        FragU pf;
        pf.u[0] = hi ? sB0 : A0;
        pf.u[1] = hi ? sB1 : A1;
        pf.u[2] = hi ? B0 : sA0;
        pf.u[3] = hi ? B1 : sA1;
        bf16x8 vf = *(const bf16x8*)&vt[lq][t * 16 + hi * 8];
        oacc = __builtin_amdgcn_mfma_f32_32x32x16_bf16(vf, pf.v, oacc, 0, 0, 0);
    }

    const float wt = sims_l[w * 32 + lq] / lsum;
    if (DENSE) {
        ushort_t* orow = O16 + (size_t)dp_l[w * 32 + lq] * C_ + h * HD_ + 4 * hi;
        #pragma unroll
        for (int g = 0; g < 4; g++) {
            uint2 pr;
            pr.x = pk2(oacc[4*g + 0] * wt, oacc[4*g + 1] * wt);
            pr.y = pk2(oacc[4*g + 2] * wt, oacc[4*g + 3] * wt);
            *(uint2*)(orow + 8 * g) = pr;
        }
    } else {
        float* drow = tmp + ((size_t)(b * HW_) + qrow) * C_ + h * HD_;
        #pragma unroll
        for (int r = 0; r < 16; r++) {
            int c = (r & 3) + 8 * (r >> 2) + 4 * hi;
            atomicAdd(&drow[c], oacc[r] * wt);
        }
    }
}

// ---------------- fallback attention (strided atomics straight to out) ----------------
__global__ __launch_bounds__(128) void k_attn_fb(
    const float* __restrict__ qkv, const int* __restrict__ idxb,
    const float* __restrict__ sims, float* __restrict__ dst)
{
    const int sp = blockIdx.x, h = blockIdx.y, b = blockIdx.z;
    __shared__ float k_l[TOPK_][HD_];
    __shared__ float vw_l[TOPK_][HD_];
    __shared__ float sims_l[TOPK_];
    __shared__ int idx_l[TOPK_];
    const int tid = threadIdx.x;
    const int roff = (b * NSP_ + sp) * TOPK_;
    idx_l[tid] = idxb[roff + tid];
    sims_l[tid] = sims[roff + tid];
    __syncthreads();
    const float* base = qkv + (size_t)b * HW_ * 768;
    #pragma unroll
    for (int it = 0; it < 8; it++) {
        int flat = it * 128 + tid;
        int s = flat >> 3, c4 = (flat & 7) * 4;
        const float* krow = base + (size_t)idx_l[s] * 768 + 256 + h * HD_ + c4;
        *(float4*)&k_l[s][c4] = *(const float4*)krow;
        const float* vrow = base + (size_t)idx_l[s] * 768 + 512 + h * HD_ + c4;
        float4 vv = *(const float4*)vrow;
        float wgt = sims_l[s];
        *(float4*)&vw_l[s][c4] = make_float4(vv.x * wgt, vv.y * wgt, vv.z * wgt, vv.w * wgt);
    }
    float q[HD_];
    const int pix = idx_l[tid];
    const float* qrow = base + (size_t)pix * 768 + h * HD_;
    #pragma unroll
    for (int j = 0; j < 8; j++) {
        float4 t4 = *(const float4*)(qrow + j * 4);
        q[j*4] = t4.x; q[j*4+1] = t4.y; q[j*4+2] = t4.z; q[j*4+3] = t4.w;
    }
    __syncthreads();
    float m = -1e30f, l = 0.f, acc[HD_];
    #pragma unroll
    for (int c = 0; c < HD_; c++) acc[c] = 0.f;
    for (int s = 0; s < TOPK_; s++) {
        float d = 0.f;
        #pragma unroll
        for (int c4 = 0; c4 < 8; c4++) {
            float4 kk4 = *(const float4*)&k_l[s][c4 * 4];
            d += q[c4*4]*kk4.x + q[c4*4+1]*kk4.y + q[c4*4+2]*kk4.z + q[c4*4+3]*kk4.w;
        }
        d *= SCALE_F;
        float mn = fmaxf(m, d);
        float fac = __expf(m - mn);
        float p = __expf(d - mn);
        l = l * fac + p;
        #pragma unroll
        for (int c4 = 0; c4 < 8; c4++) {
            float4 vv4 = *(const float4*)&vw_l[s][c4 * 4];
            acc[c4*4]   = acc[c4*4]   * fac + p * vv4.x;
            acc[c4*4+1] = acc[c4*4+1] * fac + p * vv4.y;
            acc[c4*4+2] = acc[c4*4+2] * fac + p * vv4.z;
            acc[c4*4+3] = acc[c4*4+3] * fac + p * vv4.w;
        }
        m = mn;
    }
    const float wt = sims_l[tid] / l;
    float* dbase = dst + ((size_t)b * C_ + h * HD_) * HW_ + pix;
    #pragma unroll
    for (int c = 0; c < HD_; c++) atomicAdd(dbase + (size_t)c * HW_, acc[c] * wt);
}

// ---------------- final (CSR gather, bf16 qkv, CONTIGUOUS rows) ----------------
__global__ __launch_bounds__(256) void k_final216(
    const ushort_t* __restrict__ qkv16, const ushort_t* __restrict__ O16,
    const int* __restrict__ cnt, const int* __restrict__ offs,
    float* __restrict__ out)
{
    const int b = blockIdx.z;
    const int p0 = blockIdx.x * 64, c0 = blockIdx.y * 64;
    __shared__ float t[64][65];
    const int tid = threadIdx.x;
    const int cc = tid & 63;
    #pragma unroll
    for (int it = 0; it < 16; it++) {
        int r = it * 4 + (tid >> 6);
        int p = p0 + r;
        float val = bf2f(qkv16[((size_t)b * HW_ + p) * 768 + 512 + c0 + cc]);
        int n = cnt[b * HW_ + p];
        const ushort_t* ob = O16 + ((size_t)b * (NSP_ * TOPK_) + offs[b * HW_ + p]) * C_ + c0 + cc;
        for (int j = 0; j < n; j++)
            val += bf2f(ob[(size_t)j * C_]);
        t[r][cc] = val;
    }
    __syncthreads();
    #pragma unroll
    for (int it = 0; it < 16; it++) {
        int flat = it * 256 + tid;
        int rr = flat >> 6, pp = flat & 63;
        out[((size_t)b * C_ + c0 + rr) * HW_ + p0 + pp] = t[pp][rr];
    }
}

// ---------------- final (CSR gather, fp32 qkv — tier 2, CONTIGUOUS rows) ----------------
__global__ __launch_bounds__(256) void k_final2(
    const float* __restrict__ qkv, const ushort_t* __restrict__ O16,
    const int* __restrict__ cnt, const int* __restrict__ offs,
    float* __restrict__ out)
{
    const int b = blockIdx.z;
    const int p0 = blockIdx.x * 64, c0 = blockIdx.y * 64;
    __shared__ float t[64][65];
    const int tid = threadIdx.x;
    const int cc = tid & 63;
    #pragma unroll
    for (int it = 0; it < 16; it++) {
        int r = it * 4 + (tid >> 6);
        int p = p0 + r;
        float val = qkv[((size_t)b * HW_ + p) * 768 + 512 + c0 + cc];
        int n = cnt[b * HW_ + p];
        const ushort_t* ob = O16 + ((size_t)b * (NSP_ * TOPK_) + offs[b * HW_ + p]) * C_ + c0 + cc;
        for (int j = 0; j < n; j++)
            val += bf2f(ob[(size_t)j * C_]);
        t[r][cc] = val;
    }
    __syncthreads();
    #pragma unroll
    for (int it = 0; it < 16; it++) {
        int flat = it * 256 + tid;
        int rr = flat >> 6, pp = flat & 63;
        out[((size_t)b * C_ + c0 + rr) * HW_ + p0 + pp] = t[pp][rr];
    }
}

// ---------------- final (tmp variant) ----------------
__global__ __launch_bounds__(256) void k_final(const float* __restrict__ qkv,
                                               const float* __restrict__ tmp, float* __restrict__ out)
{
    const int b = blockIdx.z;
    const int p0 = blockIdx.x * 64, c0 = blockIdx.y * 64;
    __shared__ float t[64][65];
    const int tid = threadIdx.x;
    #pragma unroll
    for (int it = 0; it < 16; it++) {
        int flat = it * 256 + tid;
        int r = flat >> 6, cc2 = flat & 63;
        float v = qkv[((size_t)b * HW_ + p0 + r) * 768 + 512 + c0 + cc2]
                + tmp[((size_t)b * HW_ + p0 + r) * C_ + c0 + cc2];
        t[r][cc2] = v;
    }
    __syncthreads();
    #pragma unroll
    for (int it = 0; it < 16; it++) {
        int flat = it * 256 + tid;
        int rr = flat >> 6, pp = flat & 63;
        out[((size_t)b * C_ + c0 + rr) * HW_ + p0 + pp] = t[pp][rr];
    }
}

__global__ __launch_bounds__(256) void k_vinit(const float* __restrict__ qkv, float* __restrict__ out)
{
    const int b = blockIdx.z;
    const int p0 = blockIdx.x * 64, c0 = blockIdx.y * 64;
    __shared__ float t[64][65];
    const int tid = threadIdx.x;
    #pragma unroll
    for (int it = 0; it < 16; it++) {
        int flat = it * 256 + tid;
        int r = flat >> 6, cc2 = flat & 63;
        t[r][cc2] = qkv[((size_t)b * HW_ + p0 + r) * 768 + 512 + c0 + cc2];
    }
    __syncthreads();
    #pragma unroll
    for (int it = 0; it < 16; it++) {
        int flat = it * 256 + tid;
        int rr = flat >> 6, pp = flat & 63;
        out[((size_t)b * C_ + c0 + rr) * HW_ + p0 + pp] = t[pp][rr];
    }
}

extern "C" void kernel_launch(void* const* d_in, const int* in_sizes, int n_in,
                              void* d_out, int out_size, void* d_ws, size_t ws_size,
                              hipStream_t stream)
{
    (void)in_sizes; (void)n_in; (void)out_size;
    const float* x     = (const float*)d_in[0];
    const float* aff   = (const float*)d_in[1];
    const float* gamma = (const float*)d_in[2];
    const float* beta  = (const float*)d_in[3];
    const float* wq    = (const float*)d_in[4];
    const float* wk    = (const float*)d_in[5];
    const float* wv    = (const float*)d_in[6];
    float* out = (float*)d_out;
    float* ws  = (float*)d_ws;

    const size_t n_mu   = (size_t)2 * B_ * HW_;
    const size_t n_qkv  = (size_t)B_ * HW_ * 768;
    const size_t n_idx  = (size_t)B_ * NSP_ * TOPK_;
    const size_t n_o16  = (size_t)B_ * NSP_ * TOPK_ * C_ / 2;
    const size_t n_pix  = (size_t)B_ * HW_;
    const size_t n_w2f  = (size_t)768 * C_;
    const size_t n_tmp  = (size_t)B_ * HW_ * C_;

    float*    mu_rstd = ws;
    float*    qkv     = ws + n_mu;
    ushort_t* qkv16   = (ushort_t*)(ws + n_mu);
    int*      idxb    = (int*)(ws + n_mu + n_qkv);
    float*    sims    = ws + n_mu + n_qkv + n_idx;
    float*    big     = ws + n_mu + n_qkv + 2 * n_idx;
    ushort_t* O16     = (ushort_t*)big;
    ushort_t* xf      = (ushort_t*)big;
    int*      cnt     = (int*)(big + n_o16);
    int*      offs    = cnt + n_pix;
    int*      cursor  = offs + n_pix;
    int*      dpos    = cursor + n_pix;
    ushort_t* wf      = (ushort_t*)(dpos + n_idx);

    const size_t need_t1  = (n_mu + n_qkv + 2 * n_idx + n_o16 + 3 * n_pix + n_idx + n_w2f) * 4;
    const size_t need_t2  = (n_mu + n_qkv + 2 * n_idx + n_o16 + 3 * n_pix + n_idx) * 4;
    const size_t need_mid = (n_mu + n_qkv + 2 * n_idx + n_tmp) * 4;

    if (ws_size >= need_t1) {
        k_wsplit16<<<dim3(24), 256, 0, stream>>>(wq, wk, wv, wf);
        k_lnsplit16<<<dim3(HW_ / 32, B_), 256, 0, stream>>>(x, gamma, beta, xf);
        k_qkv_mfma16<<<dim3(HW_ / 128, 768 / 128, B_), 256, 0, stream>>>(xf, wf, qkv16);
        k_topk<<<dim3(B_ * NSP_), 512, 0, stream>>>((const unsigned*)aff, idxb, sims);
        hipMemsetAsync(cnt, 0, 3 * n_pix * 4, stream);
        dim3 gsp(NSP_, B_);
        k_count<<<gsp, 128, 0, stream>>>(idxb, cnt);
        k_scan<<<dim3(B_), 1024, 0, stream>>>(cnt, offs);
        k_fill<<<gsp, 128, 0, stream>>>(idxb, offs, cursor, dpos);
        dim3 ga(NSP_, HEADS_, B_);
        k_attn16<<<ga, 256, 0, stream>>>(qkv16, idxb, dpos, sims, O16);
        dim3 gf(HW_ / 64, C_ / 64, B_);
        k_final216<<<gf, 256, 0, stream>>>(qkv16, O16, cnt, offs, out);
    } else if (ws_size >= need_t2) {
        k_meanvar<<<dim3((B_ * HW_) / 256), 256, 0, stream>>>(x, mu_rstd);
        dim3 gg(HW_ / GBM, 768 / GBN, B_);
        k_qkv_gemm<<<gg, 256, 0, stream>>>(x, mu_rstd, gamma, beta, wq, wk, wv, qkv);
        k_topk<<<dim3(B_ * NSP_), 512, 0, stream>>>((const unsigned*)aff, idxb, sims);
        hipMemsetAsync(cnt, 0, 3 * n_pix * 4, stream);
        dim3 gsp(NSP_, B_);
        k_count<<<gsp, 128, 0, stream>>>(idxb, cnt);
        k_scan<<<dim3(B_), 1024, 0, stream>>>(cnt, offs);
        k_fill<<<gsp, 128, 0, stream>>>(idxb, offs, cursor, dpos);
        dim3 ga(NSP_, HEADS_, B_);
        k_attn_mfma<true><<<ga, 256, 0, stream>>>(qkv, idxb, dpos, sims, O16, nullptr);
        dim3 gf(HW_ / 64, C_ / 64, B_);
        k_final2<<<gf, 256, 0, stream>>>(qkv, O16, cnt, offs, out);
    } else if (ws_size >= need_mid) {
        k_meanvar<<<dim3((B_ * HW_) / 256), 256, 0, stream>>>(x, mu_rstd);
        dim3 gg(HW_ / GBM, 768 / GBN, B_);
        k_qkv_gemm<<<gg, 256, 0, stream>>>(x, mu_rstd, gamma, beta, wq, wk, wv, qkv);
        k_topk<<<dim3(B_ * NSP_), 512, 0, stream>>>((const unsigned*)aff, idxb, sims);
        float* tmp = big;
        hipMemsetAsync(tmp, 0, n_tmp * 4, stream);
        dim3 ga(NSP_, HEADS_, B_);
        k_attn_mfma<false><<<ga, 256, 0, stream>>>(qkv, idxb, nullptr, sims, nullptr, tmp);
        dim3 gf(HW_ / 64, C_ / 64, B_);
        k_final<<<gf, 256, 0, stream>>>(qkv, tmp, out);
    } else {
        k_meanvar<<<dim3((B_ * HW_) / 256), 256, 0, stream>>>(x, mu_rstd);
        dim3 gg(HW_ / GBM, 768 / GBN, B_);
        k_qkv_gemm<<<gg, 256, 0, stream>>>(x, mu_rstd, gamma, beta, wq, wk, wv, qkv);
        k_topk<<<dim3(B_ * NSP_), 512, 0, stream>>>((const unsigned*)aff, idxb, sims);
        dim3 gf(HW_ / 64, C_ / 64, B_);
        k_vinit<<<gf, 256, 0, stream>>>(qkv, out);
        dim3 ga(NSP_, HEADS_, B_);
        k_attn_fb<<<ga, 128, 0, stream>>>(qkv, idxb, sims, out);
    }
}

// Round 22
// 158.977 us; speedup vs baseline: 1.8985x; 1.8985x over previous
//
#include <hip/hip_runtime.h>
#include <hip/hip_bf16.h>

#define B_ 2
#define C_ 256
#define H_ 128
#define W_ 128
#define HW_ 16384
#define QK_ 256
#define HEADS_ 8
#define HD_ 32
#define TOPK_ 128
#define NSP_ 256
#define SCALE_F 0.17677669529663687f
#define SC2_F 0.25500299976f        // SCALE_F * log2(e)
#define EPS_ 1e-6f

typedef __attribute__((ext_vector_type(16))) float f32x16;
typedef __attribute__((ext_vector_type(8))) short bf16x8;
typedef unsigned short ushort_t;
union FragU { unsigned int u[4]; bf16x8 v; };

// manual f32 -> bf16 (round-to-nearest-even), pure VALU, no asm (fallback tiers)
__device__ __forceinline__ ushort_t f2bf(float x)
{
    unsigned u = __float_as_uint(x);
    return (ushort_t)((u + 0x7fffu + ((u >> 16) & 1u)) >> 16);
}
__device__ __forceinline__ float bf2f(ushort_t h)
{
    return __uint_as_float((unsigned)h << 16);
}
__device__ __forceinline__ unsigned pk2(float a, float b)
{
    return (unsigned)f2bf(a) | ((unsigned)f2bf(b) << 16);
}

// native pair conversion: compiler emits v_cvt_pk_bf16_f32 (RNE), AGPR-safe
__device__ __forceinline__ unsigned pk2n(float a, float b)
{
    __hip_bfloat162 h2 = __float22bfloat162_rn(make_float2(a, b));
    union { __hip_bfloat162 h; unsigned u; } c;
    c.h = h2;
    return c.u;
}

// cross-half exchange: o0 = hi ? partner(b) : a ; o1 = hi ? b : partner(a)
__device__ __forceinline__ void half_swap(unsigned a, unsigned b,
                                          unsigned& o0, unsigned& o1, int hi)
{
#if __has_builtin(__builtin_amdgcn_permlane32_swap)
    auto r = __builtin_amdgcn_permlane32_swap(a, b, false, false);
    o0 = (unsigned)r[0];
    o1 = (unsigned)r[1];
#else
    unsigned sa = (unsigned)__shfl_xor((int)a, 32);
    unsigned sb = (unsigned)__shfl_xor((int)b, 32);
    o0 = hi ? sb : a;
    o1 = hi ? b : sa;
#endif
}

// fragment-linear layout: frag[panel][ks][lane] of bf16x8 (16B each)
__device__ __forceinline__ size_t frag_off(int panel, int ks, int lane)
{
    return (((size_t)panel * 16 + ks) * 64 + lane) * 8;
}

// split 8 f32 into bf16 hi + bf16 residual fragments (fp32-emulation, fallback tiers)
__device__ __forceinline__ void split8(const float* f, FragU& hi, FragU& lo)
{
    #pragma unroll
    for (int j = 0; j < 4; j++) {
        ushort_t h0 = f2bf(f[2*j]);
        ushort_t h1 = f2bf(f[2*j+1]);
        hi.u[j] = (unsigned)h0 | ((unsigned)h1 << 16);
        lo.u[j] = pk2(f[2*j] - bf2f(h0), f[2*j+1] - bf2f(h1));
    }
}

// ---------------- mean / rstd per pixel (fallback tiers only) ----------------
__global__ __launch_bounds__(256) void k_meanvar(const float* __restrict__ x, float* __restrict__ mu_rstd)
{
    int p = blockIdx.x * 256 + threadIdx.x;
    int b = p >> 14, pp = p & (HW_ - 1);
    const float* xb = x + (size_t)b * C_ * HW_ + pp;
    float s = 0.f, s2 = 0.f;
    for (int c = 0; c < C_; c++) {
        float v = xb[(size_t)c * HW_];
        s += v; s2 += v * v;
    }
    float mu = s * (1.f / C_);
    float var = s2 * (1.f / C_) - mu * mu;
    float rstd = rsqrtf(var + EPS_);
    mu_rstd[2 * p] = mu;
    mu_rstd[2 * p + 1] = rstd;
}

// ---------------- weight -> bf16 fragment layout: wf[panel(24)][ks][lane] ----------------
__global__ __launch_bounds__(256) void k_wsplit16(
    const float* __restrict__ wq, const float* __restrict__ wk, const float* __restrict__ wv,
    ushort_t* __restrict__ wf)
{
    const int panel = blockIdx.x;                 // 0..23
    const int lm = threadIdx.x & 31;
    const int kg = threadIdx.x >> 5;
    const int k0 = kg * 32;
    const int n = panel * 32 + lm;
    const float* wr = (n < 256) ? (wq + (size_t)n * C_)
                   : (n < 512) ? (wk + (size_t)(n - 256) * C_)
                               : (wv + (size_t)(n - 512) * C_);
    float v[32];
    #pragma unroll
    for (int j4 = 0; j4 < 8; j4++) {
        float4 t = *(const float4*)(wr + k0 + j4 * 4);
        v[j4*4+0] = t.x; v[j4*4+1] = t.y; v[j4*4+2] = t.z; v[j4*4+3] = t.w;
    }
    uint4 hv[4];
    unsigned* hp = (unsigned*)hv;
    #pragma unroll
    for (int jp = 0; jp < 16; jp++)
        hp[jp] = pk2n(v[2*jp], v[2*jp+1]);
    #pragma unroll
    for (int q = 0; q < 4; q++) {
        const int kk = k0 + 8 * q;
        const int ks = kk >> 4;
        const int hi = (kk >> 3) & 1;
        *(uint4*)(wf + frag_off(panel, ks, lm + 32 * hi)) = hv[q];
    }
}

// ---------------- fused meanvar + LN -> bf16 fragment layout ----------------
__global__ __launch_bounds__(256) void k_lnsplit16(
    const float* __restrict__ x, const float* __restrict__ gamma, const float* __restrict__ beta,
    ushort_t* __restrict__ xf)
{
    const int b = blockIdx.y;
    const int m0 = blockIdx.x * 32;
    const int lm = threadIdx.x & 31;
    const int kg = threadIdx.x >> 5;
    const int k0 = kg * 32;
    const int m = m0 + lm;
    const float* xb = x + (size_t)b * C_ * HW_ + m;
    __shared__ float g_l[C_], b_l[C_];
    __shared__ float red[2][8][32];
    g_l[threadIdx.x] = gamma[threadIdx.x];
    b_l[threadIdx.x] = beta[threadIdx.x];

    float v[32];
    float s = 0.f, s2 = 0.f;
    #pragma unroll
    for (int j = 0; j < 32; j++) {
        v[j] = xb[(size_t)(k0 + j) * HW_];
        s += v[j]; s2 += v[j] * v[j];
    }
    red[0][kg][lm] = s; red[1][kg][lm] = s2;
    __syncthreads();
    float ts = 0.f, ts2 = 0.f;
    #pragma unroll
    for (int g = 0; g < 8; g++) { ts += red[0][g][lm]; ts2 += red[1][g][lm]; }
    const float mu = ts * (1.f / C_);
    const float var = ts2 * (1.f / C_) - mu * mu;
    const float rstd = rsqrtf(var + EPS_);

    uint4 hv[4];
    unsigned* hp = (unsigned*)hv;
    #pragma unroll
    for (int jp = 0; jp < 16; jp++) {
        float l0 = (v[2*jp]   - mu) * rstd * g_l[k0 + 2*jp]   + b_l[k0 + 2*jp];
        float l1 = (v[2*jp+1] - mu) * rstd * g_l[k0 + 2*jp+1] + b_l[k0 + 2*jp+1];
        hp[jp] = pk2n(l0, l1);
    }
    const int panel = b * (HW_ / 32) + blockIdx.x;
    #pragma unroll
    for (int q = 0; q < 4; q++) {
        const int kk = k0 + 8 * q;
        const int ks = kk >> 4;
        const int hi = (kk >> 3) & 1;
        *(uint4*)(xf + frag_off(panel, ks, lm + 32 * hi)) = hv[q];
    }
}

// ---------------- MFMA QKV GEMM (pure bf16, fragment-linear operands, bf16 out) ----------------
__global__ __launch_bounds__(256) void k_qkv_mfma16(
    const ushort_t* __restrict__ xf, const ushort_t* __restrict__ wf,
    ushort_t* __restrict__ qkv16)
{
    const int b = blockIdx.z;
    const int m0 = blockIdx.x * 128, n0 = blockIdx.y * 128;
    const int tid = threadIdx.x;
    const int lane = tid & 63, wv = tid >> 6;
    const int wr = wv >> 1, wc = wv & 1;
    const int lm = lane & 31;

    const int pa0 = b * (HW_ / 32) + (m0 >> 5) + wr * 2;
    const int pa1 = pa0 + 1;
    const int pb0 = (n0 >> 5) + wc * 2;
    const int pb1 = pb0 + 1;

    f32x16 acc00, acc01, acc10, acc11;
    #pragma unroll
    for (int r = 0; r < 16; r++) { acc00[r] = 0.f; acc01[r] = 0.f; acc10[r] = 0.f; acc11[r] = 0.f; }

    #pragma unroll 8
    for (int ks = 0; ks < 16; ks++) {
        bf16x8 a0 = *(const bf16x8*)(xf + frag_off(pa0, ks, lane));
        bf16x8 a1 = *(const bf16x8*)(xf + frag_off(pa1, ks, lane));
        bf16x8 b0 = *(const bf16x8*)(wf + frag_off(pb0, ks, lane));
        bf16x8 b1 = *(const bf16x8*)(wf + frag_off(pb1, ks, lane));
        acc00 = __builtin_amdgcn_mfma_f32_32x32x16_bf16(b0, a0, acc00, 0, 0, 0);
        acc01 = __builtin_amdgcn_mfma_f32_32x32x16_bf16(b1, a0, acc01, 0, 0, 0);
        acc10 = __builtin_amdgcn_mfma_f32_32x32x16_bf16(b0, a1, acc10, 0, 0, 0);
        acc11 = __builtin_amdgcn_mfma_f32_32x32x16_bf16(b1, a1, acc11, 0, 0, 0);
    }

    const int hv4 = (lane >> 5) * 4;
    #define STORE_ACC(ACC, MT, NT) { \
        ushort_t* o = qkv16 + ((size_t)b * HW_ + m0 + wr * 64 + (MT) * 32 + lm) * 768 \
                    + n0 + wc * 64 + (NT) * 32 + hv4; \
        _Pragma("unroll") \
        for (int g = 0; g < 4; g++) { \
            uint2 pr; \
            pr.x = pk2n(ACC[4*g + 0], ACC[4*g + 1]); \
            pr.y = pk2n(ACC[4*g + 2], ACC[4*g + 3]); \
            *(uint2*)(o + 8 * g) = pr; } }
    STORE_ACC(acc00, 0, 0)
    STORE_ACC(acc01, 0, 1)
    STORE_ACC(acc10, 1, 0)
    STORE_ACC(acc11, 1, 1)
    #undef STORE_ACC
}

// ---------------- fused LN + QKV GEMM (fp32, fallback tiers) ----------------
#define GBM 128
#define GBN 128
#define GBK 8
__global__ __launch_bounds__(256) void k_qkv_gemm(
    const float* __restrict__ x, const float* __restrict__ mu_rstd,
    const float* __restrict__ gamma, const float* __restrict__ beta,
    const float* __restrict__ wq, const float* __restrict__ wk, const float* __restrict__ wv,
    float* __restrict__ qkv)
{
    const int b  = blockIdx.z;
    const int m0 = blockIdx.x * GBM;
    const int n0 = blockIdx.y * GBN;
    __shared__ float a_l[GBK][GBM + 4];
    __shared__ float b_l[GBK][GBN + 4];
    __shared__ float g_l[C_], bt_l[C_];
    const int tid = threadIdx.x;
    g_l[tid] = gamma[tid];
    bt_l[tid] = beta[tid];

    const int mm = tid & 127;
    const int kg = tid >> 7;
    const int nn = tid >> 1;
    const int kq = (tid & 1) * 4;
    const float2 mr = ((const float2*)mu_rstd)[b * HW_ + m0 + mm];
    const float* xbase = x + (size_t)b * C_ * HW_ + m0 + mm;
    const int n = n0 + nn;
    const float* wrow = (n < 256) ? (wq + (size_t)n * C_)
                     : (n < 512) ? (wk + (size_t)(n - 256) * C_)
                                 : (wv + (size_t)(n - 512) * C_);
    float acc[8][8] = {};
    const int tx = tid & 15, ty = tid >> 4;

    for (int kt = 0; kt < C_; kt += GBK) {
        __syncthreads();
        #pragma unroll
        for (int j = 0; j < 4; j++) {
            int kk = kg + j * 2;
            int c = kt + kk;
            float xv = xbase[(size_t)c * HW_];
            a_l[kk][mm] = (xv - mr.x) * mr.y * g_l[c] + bt_l[c];
        }
        float4 w4 = *(const float4*)(wrow + kt + kq);
        b_l[kq + 0][nn] = w4.x; b_l[kq + 1][nn] = w4.y;
        b_l[kq + 2][nn] = w4.z; b_l[kq + 3][nn] = w4.w;
        __syncthreads();
        #pragma unroll
        for (int kk = 0; kk < GBK; kk++) {
            float4 a0 = *(const float4*)&a_l[kk][ty * 8];
            float4 a1 = *(const float4*)&a_l[kk][ty * 8 + 4];
            float4 b0 = *(const float4*)&b_l[kk][tx * 8];
            float4 b1 = *(const float4*)&b_l[kk][tx * 8 + 4];
            float av[8] = {a0.x,a0.y,a0.z,a0.w,a1.x,a1.y,a1.z,a1.w};
            float bv[8] = {b0.x,b0.y,b0.z,b0.w,b1.x,b1.y,b1.z,b1.w};
            #pragma unroll
            for (int i = 0; i < 8; i++)
                #pragma unroll
                for (int jj = 0; jj < 8; jj++)
                    acc[i][jj] += av[i] * bv[jj];
        }
    }
    float* out0 = qkv + ((size_t)b * HW_ + m0 + ty * 8) * 768 + n0 + tx * 8;
    #pragma unroll
    for (int i = 0; i < 8; i++) {
        *(float4*)(out0 + (size_t)i * 768)     = make_float4(acc[i][0], acc[i][1], acc[i][2], acc[i][3]);
        *(float4*)(out0 + (size_t)i * 768 + 4) = make_float4(acc[i][4], acc[i][5], acc[i][6], acc[i][7]);
    }
}

// ---------------- exact top-128: radix-256, 8 waves, bank-staggered histograms ----------------
__device__ __forceinline__ unsigned fkeyu(unsigned u)
{
    return (u & 0x80000000u) ? ~u : (u | 0x80000000u);
}
__device__ __forceinline__ unsigned ifkey(unsigned k)
{
    return (k & 0x80000000u) ? (k ^ 0x80000000u) : ~k;
}

__global__ __launch_bounds__(512) void k_topk(const unsigned* __restrict__ aff,
                                              int* __restrict__ idxo, float* __restrict__ simso)
{
    const int row = blockIdx.x;
    const int tid = threadIdx.x;
    const int lane = tid & 63, wid = tid >> 6;       // 8 waves
    __shared__ __align__(16) unsigned key_l[HW_];    // 64 KB
    __shared__ unsigned hist[8][257];                // stride 257 => same bin spans 8 banks
    __shared__ unsigned sh_prefix;
    __shared__ int sh_need;
    __shared__ int partG[8], partE[8];

    // stage fkeys once (coalesced uint4)
    const uint4* a4 = (const uint4*)(aff + (size_t)row * HW_);
    #pragma unroll 8
    for (int j = 0; j < 8; j++) {
        int i4 = j * 512 + tid;
        uint4 v = a4[i4];
        key_l[4 * i4 + 0] = fkeyu(v.x);
        key_l[4 * i4 + 1] = fkeyu(v.y);
        key_l[4 * i4 + 2] = fkeyu(v.z);
        key_l[4 * i4 + 3] = fkeyu(v.w);
    }
    for (int i = tid; i < 8 * 257; i += 512) ((unsigned*)hist)[i] = 0u;
    if (tid == 0) { sh_prefix = 0u; sh_need = TOPK_; }
    __syncthreads();

    const int qbase = wid * 2048;                    // each wave owns 2048 keys

    // pass-0 histogram (full array, top 8 bits), per-wave sub-histogram
    #pragma unroll 8
    for (int j = 0; j < 8; j++) {
        uint4 k4 = *(const uint4*)&key_l[qbase + j * 256 + lane * 4];
        #pragma unroll
        for (int e = 0; e < 4; e++)
            atomicAdd(&hist[wid][((const unsigned*)&k4)[e] >> 24], 1u);
    }
    __syncthreads();

    for (int pass = 0; pass < 4; pass++) {
        if (wid == 0) {
            const unsigned pref = sh_prefix;
            const unsigned need = (unsigned)sh_need;
            unsigned c[4]; unsigned loc = 0;
            #pragma unroll
            for (int i = 0; i < 4; i++) {
                unsigned t = 0;
                #pragma unroll
                for (int hh = 0; hh < 8; hh++) t += hist[hh][lane*4+i];
                c[i] = t;
                loc += t;
            }
            unsigned s = loc;
            #pragma unroll
            for (int off = 1; off < 64; off <<= 1) {
                unsigned t = (unsigned)__shfl_down((int)s, off);
                if (lane + off < 64) s += t;
            }
            unsigned run = s - loc;
            #pragma unroll
            for (int i = 3; i >= 0; i--) {
                unsigned incl = run + c[i];
                if (incl >= need && run < need) {
                    sh_prefix = (pref << 8) | (unsigned)(lane * 4 + i);
                    sh_need = (int)(need - run);
                }
                run = incl;
            }
        }
        __syncthreads();
        if (pass == 3) break;

        const unsigned prefT = sh_prefix;
        const int shift = 24 - 8 * pass;
        for (int i = tid; i < 8 * 257; i += 512) ((unsigned*)hist)[i] = 0u;
        __syncthreads();
        const int nshift = shift - 8;
        #pragma unroll 8
        for (int j = 0; j < 8; j++) {
            uint4 k4 = *(const uint4*)&key_l[qbase + j * 256 + lane * 4];
            #pragma unroll
            for (int e = 0; e < 4; e++) {
                unsigned key = ((const unsigned*)&k4)[e];
                if ((key >> shift) == prefT)
                    atomicAdd(&hist[wid][(key >> nshift) & 255u], 1u);
            }
        }
        __syncthreads();
    }

    const unsigned T = sh_prefix;
    const int e_take = sh_need;

    int cg = 0, ce = 0;
    #pragma unroll 8
    for (int j = 0; j < 8; j++) {
        uint4 k4 = *(const uint4*)&key_l[qbase + j * 256 + lane * 4];
        #pragma unroll
        for (int e = 0; e < 4; e++) {
            unsigned key = ((const unsigned*)&k4)[e];
            cg += (key > T);
            ce += (key == T);
        }
    }
    #pragma unroll
    for (int o = 32; o >= 1; o >>= 1) { cg += __shfl_xor(cg, o); ce += __shfl_xor(ce, o); }
    if (lane == 0) { partG[wid] = cg; partE[wid] = ce; }
    __syncthreads();

    int gpre = 0, epre = 0;
    for (int q = 0; q < wid; q++) { gpre += partG[q]; epre += partE[q]; }
    int base = gpre + ((epre < e_take) ? epre : e_take);
    int rem_eq = e_take - epre;
    if (rem_eq < 0) rem_eq = 0;
    if (rem_eq > ce) rem_eq = ce;

    int* orow = idxo + (size_t)row * TOPK_;
    float* srow = simso + (size_t)row * TOPK_;
    const unsigned long long ltm = (1ULL << lane) - 1ULL;

    for (int j = 0; j < 32; j++) {
        const int i = qbase + j * 64 + lane;
        const unsigned key = key_l[i];
        const bool gt = key > T;
        const bool eq = (key == T);
        const unsigned long long bg = __ballot(gt);
        const unsigned long long be = __ballot(eq);
        const int cgc = __popcll(bg);
        const int cec = __popcll(be);
        if (gt) {
            int slot = base + __popcll(bg & ltm);
            orow[slot] = i; srow[slot] = __uint_as_float(ifkey(key));
        }
        if (eq && rem_eq > 0) {
            int r = __popcll(be & ltm);
            if (r < rem_eq) {
                int slot = base + cgc + r;
                orow[slot] = i; srow[slot] = __uint_as_float(ifkey(key));
            }
        }
        const int etk = (cec < rem_eq) ? cec : rem_eq;
        base += cgc + etk;
        rem_eq -= etk;
    }
}

// ---------------- CSR inverse-index construction ----------------
__global__ __launch_bounds__(128) void k_count(const int* __restrict__ idxb, int* __restrict__ cnt)
{
    const int sp = blockIdx.x, b = blockIdx.y;
    int pix = idxb[(b * NSP_ + sp) * TOPK_ + threadIdx.x];
    atomicAdd(&cnt[b * HW_ + pix], 1);
}

__global__ __launch_bounds__(1024) void k_scan(const int* __restrict__ cnt, int* __restrict__ offs)
{
    const int b = blockIdx.x;
    const int tid = threadIdx.x;
    __shared__ int sc[1024];
    const int base = b * HW_;
    int loc[16];
    int s = 0;
    #pragma unroll
    for (int i = 0; i < 16; i++) {
        int c = cnt[base + tid * 16 + i];
        loc[i] = s;
        s += c;
    }
    sc[tid] = s;
    __syncthreads();
    for (int off = 1; off < 1024; off <<= 1) {
        int add = (tid >= off) ? sc[tid - off] : 0;
        __syncthreads();
        sc[tid] += add;
        __syncthreads();
    }
    int excl = sc[tid] - s;
    #pragma unroll
    for (int i = 0; i < 16; i++)
        offs[base + tid * 16 + i] = excl + loc[i];
}

// fill: compute each slot's DESTINATION position in CSR order (dpos), global row id
__global__ __launch_bounds__(128) void k_fill(const int* __restrict__ idxb, const int* __restrict__ offs,
                                              int* __restrict__ cursor, int* __restrict__ dpos)
{
    const int sp = blockIdx.x, b = blockIdx.y;
    const int slot = threadIdx.x;
    const int gid = (b * NSP_ + sp) * TOPK_ + slot;
    int pix = idxb[gid];
    int pos = atomicAdd(&cursor[b * HW_ + pix], 1);
    dpos[gid] = b * (NSP_ * TOPK_) + offs[b * HW_ + pix] + pos;
}

// ---------------- MFMA attention, bf16 qkv (tier 1) ----------------
__global__ __launch_bounds__(256, 4) void k_attn16(
    const ushort_t* __restrict__ qkv16, const int* __restrict__ idxb,
    const int* __restrict__ dpos, const float* __restrict__ sims,
    ushort_t* __restrict__ O16)
{
    const int sp = blockIdx.x, h = blockIdx.y, b = blockIdx.z;
    __shared__ int idx_l[TOPK_];
    __shared__ int dp_l[TOPK_];
    __shared__ float sims_l[TOPK_];
    __shared__ __align__(16) ushort_t vt[HD_][TOPK_ + 8];

    const int tid = threadIdx.x;
    const int roff = (b * NSP_ + sp) * TOPK_;
    if (tid < TOPK_) {
        idx_l[tid] = idxb[roff + tid];
        dp_l[tid] = dpos[roff + tid];
        sims_l[tid] = sims[roff + tid];
    }
    __syncthreads();

    const ushort_t* qb = qkv16 + (size_t)b * HW_ * 768;

    // stage sims-weighted V^T into LDS (bf16, native pair converts)
    {
        const int s = tid >> 1, ch = (tid & 1) * 16;
        const float wgt = sims_l[s];
        const ushort_t* vrow = qb + (size_t)idx_l[s] * 768 + 512 + h * HD_ + ch;
        bf16x8 v0 = *(const bf16x8*)(vrow);
        bf16x8 v1 = *(const bf16x8*)(vrow + 8);
        #pragma unroll
        for (int jp = 0; jp < 4; jp++) {
            unsigned p0 = pk2n(bf2f((ushort_t)v0[2*jp]) * wgt, bf2f((ushort_t)v0[2*jp+1]) * wgt);
            vt[ch + 2*jp][s]     = (ushort_t)p0;
            vt[ch + 2*jp + 1][s] = (ushort_t)(p0 >> 16);
            unsigned p1 = pk2n(bf2f((ushort_t)v1[2*jp]) * wgt, bf2f((ushort_t)v1[2*jp+1]) * wgt);
            vt[ch + 8 + 2*jp][s]     = (ushort_t)p1;
            vt[ch + 8 + 2*jp + 1][s] = (ushort_t)(p1 >> 16);
        }
    }

    const int lane = tid & 63, w = tid >> 6;
    const int lq = lane & 31, hi = lane >> 5;
    const int qrow = idx_l[w * 32 + lq];

    f32x16 sacc[4];
    #pragma unroll
    for (int s = 0; s < 4; s++)
        #pragma unroll
        for (int r = 0; r < 16; r++) sacc[s][r] = 0.f;

    // QK^T: direct bf16 fragments (A = K rows, B = Q^T cols)
    #pragma unroll
    for (int t = 0; t < 2; t++) {
        bf16x8 qf = *(const bf16x8*)(qb + (size_t)qrow * 768 + h * HD_ + t * 16 + hi * 8);
        #pragma unroll
        for (int s = 0; s < 4; s++) {
            const int krow = idx_l[s * 32 + lq];
            bf16x8 kf = *(const bf16x8*)(qb + (size_t)krow * 768 + 256 + h * HD_ + t * 16 + hi * 8);
            sacc[s] = __builtin_amdgcn_mfma_f32_32x32x16_bf16(kf, qf, sacc[s], 0, 0, 0);
        }
    }

    // full softmax over s (lane holds 64 of 128; partner in lane^32)
    float m = fmaxf(sacc[0][0], sacc[0][1]);
    #pragma unroll
    for (int s = 0; s < 4; s++)
        #pragma unroll
        for (int r = (s == 0 ? 2 : 0); r < 16; r += 2)
            m = fmaxf(m, fmaxf(sacc[s][r], sacc[s][r + 1]));
    m = fmaxf(m, __shfl_xor(m, 32));
    const float mb = -m * SC2_F;                    // exp2 prescale
    float l0 = 0.f, l1 = 0.f;
    #pragma unroll
    for (int s = 0; s < 4; s++)
        #pragma unroll
        for (int r = 0; r < 16; r += 2) {
            float p0 = exp2f(fmaf(sacc[s][r],     SC2_F, mb));
            float p1 = exp2f(fmaf(sacc[s][r + 1], SC2_F, mb));
            sacc[s][r] = p0;
            sacc[s][r + 1] = p1;
            l0 += p0;
            l1 += p1;
        }
    float lsum = l0 + l1;
    lsum += __shfl_xor(lsum, 32);

    __syncthreads();   // vt ready

    f32x16 oacc;
    #pragma unroll
    for (int r = 0; r < 16; r++) oacc[r] = 0.f;

    #pragma unroll
    for (int t = 0; t < 8; t++) {
        const int st = t >> 1, rb = (t & 1) * 8;
        unsigned A0 = pk2n(sacc[st][rb + 0], sacc[st][rb + 1]);
        unsigned A1 = pk2n(sacc[st][rb + 2], sacc[st][rb + 3]);
        unsigned B0 = pk2n(sacc[st][rb + 4], sacc[st][rb + 5]);
        unsigned B1 = pk2n(sacc[st][rb + 6], sacc[st][rb + 7]);
        FragU pf;
        half_swap(A0, B0, pf.u[0], pf.u[2], hi);
        half_swap(A1, B1, pf.u[1], pf.u[3], hi);
        bf16x8 vf = *(const bf16x8*)&vt[lq][t * 16 + hi * 8];
        oacc = __builtin_amdgcn_mfma_f32_32x32x16_bf16(vf, pf.v, oacc, 0, 0, 0);
    }

    const float wt = sims_l[w * 32 + lq] / lsum;
    ushort_t* orow = O16 + (size_t)dp_l[w * 32 + lq] * C_ + h * HD_ + 4 * hi;
    #pragma unroll
    for (int g = 0; g < 4; g++) {
        uint2 pr;
        pr.x = pk2n(oacc[4*g + 0] * wt, oacc[4*g + 1] * wt);
        pr.y = pk2n(oacc[4*g + 2] * wt, oacc[4*g + 3] * wt);
        *(uint2*)(orow + 8 * g) = pr;
    }
}

// ---------------- MFMA attention, fp32 qkv (fallback tiers) ----------------
template <bool DENSE>
__global__ __launch_bounds__(256) void k_attn_mfma(
    const float* __restrict__ qkv, const int* __restrict__ idxb,
    const int* __restrict__ dpos, const float* __restrict__ sims,
    ushort_t* __restrict__ O16, float* __restrict__ tmp)
{
    const int sp = blockIdx.x, h = blockIdx.y, b = blockIdx.z;
    __shared__ int idx_l[TOPK_];
    __shared__ int dp_l[TOPK_];
    __shared__ float sims_l[TOPK_];
    __shared__ __align__(16) ushort_t vt[HD_][TOPK_ + 8];

    const int tid = threadIdx.x;
    const int roff = (b * NSP_ + sp) * TOPK_;
    if (tid < TOPK_) {
        idx_l[tid] = idxb[roff + tid];
        sims_l[tid] = sims[roff + tid];
        if (DENSE) dp_l[tid] = dpos[roff + tid];
    }
    __syncthreads();

    const float* qb = qkv + (size_t)b * HW_ * 768;

    {
        const int s = tid >> 1, ch = (tid & 1) * 16;
        const float wgt = sims_l[s];
        const float* vrow = qb + (size_t)idx_l[s] * 768 + 512 + h * HD_ + ch;
        #pragma unroll
        for (int j4 = 0; j4 < 4; j4++) {
            float4 vv = *(const float4*)(vrow + j4 * 4);
            vt[ch + j4 * 4 + 0][s] = f2bf(vv.x * wgt);
            vt[ch + j4 * 4 + 1][s] = f2bf(vv.y * wgt);
            vt[ch + j4 * 4 + 2][s] = f2bf(vv.z * wgt);
            vt[ch + j4 * 4 + 3][s] = f2bf(vv.w * wgt);
        }
    }

    const int lane = tid & 63, w = tid >> 6;
    const int lq = lane & 31, hi = lane >> 5;
    const int qrow = idx_l[w * 32 + lq];

    f32x16 sacc[4];
    #pragma unroll
    for (int s = 0; s < 4; s++)
        #pragma unroll
        for (int r = 0; r < 16; r++) sacc[s][r] = 0.f;

    #pragma unroll
    for (int t = 0; t < 2; t++) {
        const float* qp = qb + (size_t)qrow * 768 + h * HD_ + t * 16 + hi * 8;
        float q8[8];
        {
            float4 t0 = *(const float4*)qp;
            float4 t1 = *(const float4*)(qp + 4);
            q8[0]=t0.x; q8[1]=t0.y; q8[2]=t0.z; q8[3]=t0.w;
            q8[4]=t1.x; q8[5]=t1.y; q8[6]=t1.z; q8[7]=t1.w;
        }
        FragU qh, ql; split8(q8, qh, ql);
        #pragma unroll
        for (int s = 0; s < 4; s++) {
            const int krow = idx_l[s * 32 + lq];
            const float* kp = qb + (size_t)krow * 768 + 256 + h * HD_ + t * 16 + hi * 8;
            float k8[8];
            {
                float4 t0 = *(const float4*)kp;
                float4 t1 = *(const float4*)(kp + 4);
                k8[0]=t0.x; k8[1]=t0.y; k8[2]=t0.z; k8[3]=t0.w;
                k8[4]=t1.x; k8[5]=t1.y; k8[6]=t1.z; k8[7]=t1.w;
            }
            FragU kh, kl; split8(k8, kh, kl);
            sacc[s] = __builtin_amdgcn_mfma_f32_32x32x16_bf16(kh.v, qh.v, sacc[s], 0, 0, 0);
            sacc[s] = __builtin_amdgcn_mfma_f32_32x32x16_bf16(kh.v, ql.v, sacc[s], 0, 0, 0);
            sacc[s] = __builtin_amdgcn_mfma_f32_32x32x16_bf16(kl.v, qh.v, sacc[s], 0, 0, 0);
        }
    }

    float m = -1e30f;
    #pragma unroll
    for (int s = 0; s < 4; s++)
        #pragma unroll
        for (int r = 0; r < 16; r++) m = fmaxf(m, sacc[s][r]);
    m = fmaxf(m, __shfl_xor(m, 32));
    float lsum = 0.f;
    #pragma unroll
    for (int s = 0; s < 4; s++)
        #pragma unroll
        for (int r = 0; r < 16; r++) {
            float p = __expf((sacc[s][r] - m) * SCALE_F);
            sacc[s][r] = p;
            lsum += p;
        }
    lsum += __shfl_xor(lsum, 32);

    __syncthreads();

    f32x16 oacc;
    #pragma unroll
    for (int r = 0; r < 16; r++) oacc[r] = 0.f;

    #pragma unroll
    for (int t = 0; t < 8; t++) {
        const int st = t >> 1, rb = (t & 1) * 8;
        unsigned A0 = pk2(sacc[st][rb + 0], sacc[st][rb + 1]);
        unsigned A1 = pk2(sacc[st][rb + 2], sacc[st][rb + 3]);
        unsigned B0 = pk2(sacc[st][rb + 4], sacc[st][rb + 5]);
        unsigned B1 = pk2(sacc[st][rb + 6], sacc[st][rb + 7]);
        unsigned sA0 = (unsigned)__shfl_xor((int)A0, 32);
        unsigned sA1 = (unsigned)__shfl_xor((int)A1, 32);
        unsigned sB0 = (unsigned)__shfl_xor((int)B0, 32);
        unsigned sB1 = (unsigned)__shfl_xor((int)B1, 32);
        FragU pf;
        pf.u[0] = hi ? sB0 : A0;
        pf.u[1] = hi ? sB1 : A1;
        pf.u[2] = hi ? B0 : sA0;
        pf.u[3] = hi ? B1 : sA1;
        bf16x8 vf = *(const bf16x8*)&vt[lq][t * 16 + hi * 8];
        oacc = __builtin_amdgcn_mfma_f32_32x32x16_bf16(vf, pf.v, oacc, 0, 0, 0);
    }

    const float wt = sims_l[w * 32 + lq] / lsum;
    if (DENSE) {
        ushort_t* orow = O16 + (size_t)dp_l[w * 32 + lq] * C_ + h * HD_ + 4 * hi;
        #pragma unroll
        for (int g = 0; g < 4; g++) {
            uint2 pr;
            pr.x = pk2(oacc[4*g + 0] * wt, oacc[4*g + 1] * wt);
            pr.y = pk2(oacc[4*g + 2] * wt, oacc[4*g + 3] * wt);
            *(uint2*)(orow + 8 * g) = pr;
        }
    } else {
        float* drow = tmp + ((size_t)(b * HW_) + qrow) * C_ + h * HD_;
        #pragma unroll
        for (int r = 0; r < 16; r++) {
            int c = (r & 3) + 8 * (r >> 2) + 4 * hi;
            atomicAdd(&drow[c], oacc[r] * wt);
        }
    }
}

// ---------------- fallback attention (strided atomics straight to out) ----------------
__global__ __launch_bounds__(128) void k_attn_fb(
    const float* __restrict__ qkv, const int* __restrict__ idxb,
    const float* __restrict__ sims, float* __restrict__ dst)
{
    const int sp = blockIdx.x, h = blockIdx.y, b = blockIdx.z;
    __shared__ float k_l[TOPK_][HD_];
    __shared__ float vw_l[TOPK_][HD_];
    __shared__ float sims_l[TOPK_];
    __shared__ int idx_l[TOPK_];
    const int tid = threadIdx.x;
    const int roff = (b * NSP_ + sp) * TOPK_;
    idx_l[tid] = idxb[roff + tid];
    sims_l[tid] = sims[roff + tid];
    __syncthreads();
    const float* base = qkv + (size_t)b * HW_ * 768;
    #pragma unroll
    for (int it = 0; it < 8; it++) {
        int flat = it * 128 + tid;
        int s = flat >> 3, c4 = (flat & 7) * 4;
        const float* krow = base + (size_t)idx_l[s] * 768 + 256 + h * HD_ + c4;
        *(float4*)&k_l[s][c4] = *(const float4*)krow;
        const float* vrow = base + (size_t)idx_l[s] * 768 + 512 + h * HD_ + c4;
        float4 vv = *(const float4*)vrow;
        float wgt = sims_l[s];
        *(float4*)&vw_l[s][c4] = make_float4(vv.x * wgt, vv.y * wgt, vv.z * wgt, vv.w * wgt);
    }
    float q[HD_];
    const int pix = idx_l[tid];
    const float* qrow = base + (size_t)pix * 768 + h * HD_;
    #pragma unroll
    for (int j = 0; j < 8; j++) {
        float4 t4 = *(const float4*)(qrow + j * 4);
        q[j*4] = t4.x; q[j*4+1] = t4.y; q[j*4+2] = t4.z; q[j*4+3] = t4.w;
    }
    __syncthreads();
    float m = -1e30f, l = 0.f, acc[HD_];
    #pragma unroll
    for (int c = 0; c < HD_; c++) acc[c] = 0.f;
    for (int s = 0; s < TOPK_; s++) {
        float d = 0.f;
        #pragma unroll
        for (int c4 = 0; c4 < 8; c4++) {
            float4 kk4 = *(const float4*)&k_l[s][c4 * 4];
            d += q[c4*4]*kk4.x + q[c4*4+1]*kk4.y + q[c4*4+2]*kk4.z + q[c4*4+3]*kk4.w;
        }
        d *= SCALE_F;
        float mn = fmaxf(m, d);
        float fac = __expf(m - mn);
        float p = __expf(d - mn);
        l = l * fac + p;
        #pragma unroll
        for (int c4 = 0; c4 < 8; c4++) {
            float4 vv4 = *(const float4*)&vw_l[s][c4 * 4];
            acc[c4*4]   = acc[c4*4]   * fac + p * vv4.x;
            acc[c4*4+1] = acc[c4*4+1] * fac + p * vv4.y;
            acc[c4*4+2] = acc[c4*4+2] * fac + p * vv4.z;
            acc[c4*4+3] = acc[c4*4+3] * fac + p * vv4.w;
        }
        m = mn;
    }
    const float wt = sims_l[tid] / l;
    float* dbase = dst + ((size_t)b * C_ + h * HD_) * HW_ + pix;
    #pragma unroll
    for (int c = 0; c < HD_; c++) atomicAdd(dbase + (size_t)c * HW_, acc[c] * wt);
}

// ---------------- final (CSR gather, bf16 qkv, CONTIGUOUS rows) ----------------
__global__ __launch_bounds__(256) void k_final216(
    const ushort_t* __restrict__ qkv16, const ushort_t* __restrict__ O16,
    const int* __restrict__ cnt, const int* __restrict__ offs,
    float* __restrict__ out)
{
    const int b = blockIdx.z;
    const int p0 = blockIdx.x * 64, c0 = blockIdx.y * 64;
    __shared__ float t[64][65];
    const int tid = threadIdx.x;
    const int cc = tid & 63;
    #pragma unroll
    for (int it = 0; it < 16; it++) {
        int r = it * 4 + (tid >> 6);
        int p = p0 + r;
        float val = bf2f(qkv16[((size_t)b * HW_ + p) * 768 + 512 + c0 + cc]);
        int n = cnt[b * HW_ + p];
        const ushort_t* ob = O16 + ((size_t)b * (NSP_ * TOPK_) + offs[b * HW_ + p]) * C_ + c0 + cc;
        for (int j = 0; j < n; j++)
            val += bf2f(ob[(size_t)j * C_]);
        t[r][cc] = val;
    }
    __syncthreads();
    #pragma unroll
    for (int it = 0; it < 16; it++) {
        int flat = it * 256 + tid;
        int rr = flat >> 6, pp = flat & 63;
        out[((size_t)b * C_ + c0 + rr) * HW_ + p0 + pp] = t[pp][rr];
    }
}

// ---------------- final (CSR gather, fp32 qkv — tier 2, CONTIGUOUS rows) ----------------
__global__ __launch_bounds__(256) void k_final2(
    const float* __restrict__ qkv, const ushort_t* __restrict__ O16,
    const int* __restrict__ cnt, const int* __restrict__ offs,
    float* __restrict__ out)
{
    const int b = blockIdx.z;
    const int p0 = blockIdx.x * 64, c0 = blockIdx.y * 64;
    __shared__ float t[64][65];
    const int tid = threadIdx.x;
    const int cc = tid & 63;
    #pragma unroll
    for (int it = 0; it < 16; it++) {
        int r = it * 4 + (tid >> 6);
        int p = p0 + r;
        float val = qkv[((size_t)b * HW_ + p) * 768 + 512 + c0 + cc];
        int n = cnt[b * HW_ + p];
        const ushort_t* ob = O16 + ((size_t)b * (NSP_ * TOPK_) + offs[b * HW_ + p]) * C_ + c0 + cc;
        for (int j = 0; j < n; j++)
            val += bf2f(ob[(size_t)j * C_]);
        t[r][cc] = val;
    }
    __syncthreads();
    #pragma unroll
    for (int it = 0; it < 16; it++) {
        int flat = it * 256 + tid;
        int rr = flat >> 6, pp = flat & 63;
        out[((size_t)b * C_ + c0 + rr) * HW_ + p0 + pp] = t[pp][rr];
    }
}

// ---------------- final (tmp variant) ----------------
__global__ __launch_bounds__(256) void k_final(const float* __restrict__ qkv,
                                               const float* __restrict__ tmp, float* __restrict__ out)
{
    const int b = blockIdx.z;
    const int p0 = blockIdx.x * 64, c0 = blockIdx.y * 64;
    __shared__ float t[64][65];
    const int tid = threadIdx.x;
    #pragma unroll
    for (int it = 0; it < 16; it++) {
        int flat = it * 256 + tid;
        int r = flat >> 6, cc2 = flat & 63;
        float v = qkv[((size_t)b * HW_ + p0 + r) * 768 + 512 + c0 + cc2]
                + tmp[((size_t)b * HW_ + p0 + r) * C_ + c0 + cc2];
        t[r][cc2] = v;
    }
    __syncthreads();
    #pragma unroll
    for (int it = 0; it < 16; it++) {
        int flat = it * 256 + tid;
        int rr = flat >> 6, pp = flat & 63;
        out[((size_t)b * C_ + c0 + rr) * HW_ + p0 + pp] = t[pp][rr];
    }
}

__global__ __launch_bounds__(256) void k_vinit(const float* __restrict__ qkv, float* __restrict__ out)
{
    const int b = blockIdx.z;
    const int p0 = blockIdx.x * 64, c0 = blockIdx.y * 64;
    __shared__ float t[64][65];
    const int tid = threadIdx.x;
    #pragma unroll
    for (int it = 0; it < 16; it++) {
        int flat = it * 256 + tid;
        int r = flat >> 6, cc2 = flat & 63;
        t[r][cc2] = qkv[((size_t)b * HW_ + p0 + r) * 768 + 512 + c0 + cc2];
    }
    __syncthreads();
    #pragma unroll
    for (int it = 0; it < 16; it++) {
        int flat = it * 256 + tid;
        int rr = flat >> 6, pp = flat & 63;
        out[((size_t)b * C_ + c0 + rr) * HW_ + p0 + pp] = t[pp][rr];
    }
}

extern "C" void kernel_launch(void* const* d_in, const int* in_sizes, int n_in,
                              void* d_out, int out_size, void* d_ws, size_t ws_size,
                              hipStream_t stream)
{
    (void)in_sizes; (void)n_in; (void)out_size;
    const float* x     = (const float*)d_in[0];
    const float* aff   = (const float*)d_in[1];
    const float* gamma = (const float*)d_in[2];
    const float* beta  = (const float*)d_in[3];
    const float* wq    = (const float*)d_in[4];
    const float* wk    = (const float*)d_in[5];
    const float* wv    = (const float*)d_in[6];
    float* out = (float*)d_out;
    float* ws  = (float*)d_ws;

    const size_t n_mu   = (size_t)2 * B_ * HW_;
    const size_t n_qkv  = (size_t)B_ * HW_ * 768;
    const size_t n_idx  = (size_t)B_ * NSP_ * TOPK_;
    const size_t n_o16  = (size_t)B_ * NSP_ * TOPK_ * C_ / 2;
    const size_t n_pix  = (size_t)B_ * HW_;
    const size_t n_w2f  = (size_t)768 * C_;
    const size_t n_tmp  = (size_t)B_ * HW_ * C_;

    float*    mu_rstd = ws;
    float*    qkv     = ws + n_mu;
    ushort_t* qkv16   = (ushort_t*)(ws + n_mu);
    int*      idxb    = (int*)(ws + n_mu + n_qkv);
    float*    sims    = ws + n_mu + n_qkv + n_idx;
    float*    big     = ws + n_mu + n_qkv + 2 * n_idx;
    ushort_t* O16     = (ushort_t*)big;
    ushort_t* xf      = (ushort_t*)big;
    int*      cnt     = (int*)(big + n_o16);
    int*      offs    = cnt + n_pix;
    int*      cursor  = offs + n_pix;
    int*      dpos    = cursor + n_pix;
    ushort_t* wf      = (ushort_t*)(dpos + n_idx);

    const size_t need_t1  = (n_mu + n_qkv + 2 * n_idx + n_o16 + 3 * n_pix + n_idx + n_w2f) * 4;
    const size_t need_t2  = (n_mu + n_qkv + 2 * n_idx + n_o16 + 3 * n_pix + n_idx) * 4;
    const size_t need_mid = (n_mu + n_qkv + 2 * n_idx + n_tmp) * 4;

    if (ws_size >= need_t1) {
        k_wsplit16<<<dim3(24), 256, 0, stream>>>(wq, wk, wv, wf);
        k_lnsplit16<<<dim3(HW_ / 32, B_), 256, 0, stream>>>(x, gamma, beta, xf);
        k_qkv_mfma16<<<dim3(HW_ / 128, 768 / 128, B_), 256, 0, stream>>>(xf, wf, qkv16);
        k_topk<<<dim3(B_ * NSP_), 512, 0, stream>>>((const unsigned*)aff, idxb, sims);
        hipMemsetAsync(cnt, 0, 3 * n_pix * 4, stream);
        dim3 gsp(NSP_, B_);
        k_count<<<gsp, 128, 0, stream>>>(idxb, cnt);
        k_scan<<<dim3(B_), 1024, 0, stream>>>(cnt, offs);
        k_fill<<<gsp, 128, 0, stream>>>(idxb, offs, cursor, dpos);
        dim3 ga(NSP_, HEADS_, B_);
        k_attn16<<<ga, 256, 0, stream>>>(qkv16, idxb, dpos, sims, O16);
        dim3 gf(HW_ / 64, C_ / 64, B_);
        k_final216<<<gf, 256, 0, stream>>>(qkv16, O16, cnt, offs, out);
    } else if (ws_size >= need_t2) {
        k_meanvar<<<dim3((B_ * HW_) / 256), 256, 0, stream>>>(x, mu_rstd);
        dim3 gg(HW_ / GBM, 768 / GBN, B_);
        k_qkv_gemm<<<gg, 256, 0, stream>>>(x, mu_rstd, gamma, beta, wq, wk, wv, qkv);
        k_topk<<<dim3(B_ * NSP_), 512, 0, stream>>>((const unsigned*)aff, idxb, sims);
        hipMemsetAsync(cnt, 0, 3 * n_pix * 4, stream);
        dim3 gsp(NSP_, B_);
        k_count<<<gsp, 128, 0, stream>>>(idxb, cnt);
        k_scan<<<dim3(B_), 1024, 0, stream>>>(cnt, offs);
        k_fill<<<gsp, 128, 0, stream>>>(idxb, offs, cursor, dpos);
        dim3 ga(NSP_, HEADS_, B_);
        k_attn_mfma<true><<<ga, 256, 0, stream>>>(qkv, idxb, dpos, sims, O16, nullptr);
        dim3 gf(HW_ / 64, C_ / 64, B_);
        k_final2<<<gf, 256, 0, stream>>>(qkv, O16, cnt, offs, out);
    } else if (ws_size >= need_mid) {
        k_meanvar<<<dim3((B_ * HW_) / 256), 256, 0, stream>>>(x, mu_rstd);
        dim3 gg(HW_ / GBM, 768 / GBN, B_);
        k_qkv_gemm<<<gg, 256, 0, stream>>>(x, mu_rstd, gamma, beta, wq, wk, wv, qkv);
        k_topk<<<dim3(B_ * NSP_), 512, 0, stream>>>((const unsigned*)aff, idxb, sims);
        float* tmp = big;
        hipMemsetAsync(tmp, 0, n_tmp * 4, stream);
        dim3 ga(NSP_, HEADS_, B_);
        k_attn_mfma<false><<<ga, 256, 0, stream>>>(qkv, idxb, nullptr, sims, nullptr, tmp);
        dim3 gf(HW_ / 64, C_ / 64, B_);
        k_final<<<gf, 256, 0, stream>>>(qkv, tmp, out);
    } else {
        k_meanvar<<<dim3((B_ * HW_) / 256), 256, 0, stream>>>(x, mu_rstd);
        dim3 gg(HW_ / GBM, 768 / GBN, B_);
        k_qkv_gemm<<<gg, 256, 0, stream>>>(x, mu_rstd, gamma, beta, wq, wk, wv, qkv);
        k_topk<<<dim3(B_ * NSP_), 512, 0, stream>>>((const unsigned*)aff, idxb, sims);
        dim3 gf(HW_ / 64, C_ / 64, B_);
        k_vinit<<<gf, 256, 0, stream>>>(qkv, out);
        dim3 ga(NSP_, HEADS_, B_);
        k_attn_fb<<<ga, 128, 0, stream>>>(qkv, idxb, sims, out);
    }
}

// Round 23
// 156.006 us; speedup vs baseline: 1.9346x; 1.0190x over previous
//
#include <hip/hip_runtime.h>
#include <hip/hip_bf16.h>

#define B_ 2
#define C_ 256
#define H_ 128
#define W_ 128
#define HW_ 16384
#define QK_ 256
#define HEADS_ 8
#define HD_ 32
#define TOPK_ 128
#define NSP_ 256
#define SCALE_F 0.17677669529663687f
#define SC2_F 0.25500299976f        // SCALE_F * log2(e)
#define EPS_ 1e-6f

typedef __attribute__((ext_vector_type(16))) float f32x16;
typedef __attribute__((ext_vector_type(8))) short bf16x8;
typedef unsigned short ushort_t;
union FragU { unsigned int u[4]; bf16x8 v; };

// manual f32 -> bf16 (round-to-nearest-even), pure VALU, no asm (fallback tiers)
__device__ __forceinline__ ushort_t f2bf(float x)
{
    unsigned u = __float_as_uint(x);
    return (ushort_t)((u + 0x7fffu + ((u >> 16) & 1u)) >> 16);
}
__device__ __forceinline__ float bf2f(ushort_t h)
{
    return __uint_as_float((unsigned)h << 16);
}
__device__ __forceinline__ unsigned pk2(float a, float b)
{
    return (unsigned)f2bf(a) | ((unsigned)f2bf(b) << 16);
}

// native pair conversion: compiler emits v_cvt_pk_bf16_f32 (RNE), AGPR-safe
__device__ __forceinline__ unsigned pk2n(float a, float b)
{
    __hip_bfloat162 h2 = __float22bfloat162_rn(make_float2(a, b));
    union { __hip_bfloat162 h; unsigned u; } c;
    c.h = h2;
    return c.u;
}

// cross-half exchange: o0 = hi ? partner(b) : a ; o1 = hi ? b : partner(a)
__device__ __forceinline__ void half_swap(unsigned a, unsigned b,
                                          unsigned& o0, unsigned& o1, int hi)
{
#if __has_builtin(__builtin_amdgcn_permlane32_swap)
    auto r = __builtin_amdgcn_permlane32_swap(a, b, false, false);
    o0 = (unsigned)r[0];
    o1 = (unsigned)r[1];
#else
    unsigned sa = (unsigned)__shfl_xor((int)a, 32);
    unsigned sb = (unsigned)__shfl_xor((int)b, 32);
    o0 = hi ? sb : a;
    o1 = hi ? b : sa;
#endif
}

// fragment-linear layout: frag[panel][ks][lane] of bf16x8 (16B each)
__device__ __forceinline__ size_t frag_off(int panel, int ks, int lane)
{
    return (((size_t)panel * 16 + ks) * 64 + lane) * 8;
}

// split 8 f32 into bf16 hi + bf16 residual fragments (fp32-emulation, fallback tiers)
__device__ __forceinline__ void split8(const float* f, FragU& hi, FragU& lo)
{
    #pragma unroll
    for (int j = 0; j < 4; j++) {
        ushort_t h0 = f2bf(f[2*j]);
        ushort_t h1 = f2bf(f[2*j+1]);
        hi.u[j] = (unsigned)h0 | ((unsigned)h1 << 16);
        lo.u[j] = pk2(f[2*j] - bf2f(h0), f[2*j+1] - bf2f(h1));
    }
}

// ---------------- mean / rstd per pixel (fallback tiers only) ----------------
__global__ __launch_bounds__(256) void k_meanvar(const float* __restrict__ x, float* __restrict__ mu_rstd)
{
    int p = blockIdx.x * 256 + threadIdx.x;
    int b = p >> 14, pp = p & (HW_ - 1);
    const float* xb = x + (size_t)b * C_ * HW_ + pp;
    float s = 0.f, s2 = 0.f;
    for (int c = 0; c < C_; c++) {
        float v = xb[(size_t)c * HW_];
        s += v; s2 += v * v;
    }
    float mu = s * (1.f / C_);
    float var = s2 * (1.f / C_) - mu * mu;
    float rstd = rsqrtf(var + EPS_);
    mu_rstd[2 * p] = mu;
    mu_rstd[2 * p + 1] = rstd;
}

// ---------------- weight -> bf16 fragment layout: wf[panel(24)][ks][lane] ----------------
__global__ __launch_bounds__(256) void k_wsplit16(
    const float* __restrict__ wq, const float* __restrict__ wk, const float* __restrict__ wv,
    ushort_t* __restrict__ wf)
{
    const int panel = blockIdx.x;                 // 0..23
    const int lm = threadIdx.x & 31;
    const int kg = threadIdx.x >> 5;
    const int k0 = kg * 32;
    const int n = panel * 32 + lm;
    const float* wr = (n < 256) ? (wq + (size_t)n * C_)
                   : (n < 512) ? (wk + (size_t)(n - 256) * C_)
                               : (wv + (size_t)(n - 512) * C_);
    float v[32];
    #pragma unroll
    for (int j4 = 0; j4 < 8; j4++) {
        float4 t = *(const float4*)(wr + k0 + j4 * 4);
        v[j4*4+0] = t.x; v[j4*4+1] = t.y; v[j4*4+2] = t.z; v[j4*4+3] = t.w;
    }
    uint4 hv[4];
    unsigned* hp = (unsigned*)hv;
    #pragma unroll
    for (int jp = 0; jp < 16; jp++)
        hp[jp] = pk2n(v[2*jp], v[2*jp+1]);
    #pragma unroll
    for (int q = 0; q < 4; q++) {
        const int kk = k0 + 8 * q;
        const int ks = kk >> 4;
        const int hi = (kk >> 3) & 1;
        *(uint4*)(wf + frag_off(panel, ks, lm + 32 * hi)) = hv[q];
    }
}

// ---------------- fused meanvar + LN -> bf16 fragment layout ----------------
__global__ __launch_bounds__(256) void k_lnsplit16(
    const float* __restrict__ x, const float* __restrict__ gamma, const float* __restrict__ beta,
    ushort_t* __restrict__ xf)
{
    const int b = blockIdx.y;
    const int m0 = blockIdx.x * 32;
    const int lm = threadIdx.x & 31;
    const int kg = threadIdx.x >> 5;
    const int k0 = kg * 32;
    const int m = m0 + lm;
    const float* xb = x + (size_t)b * C_ * HW_ + m;
    __shared__ float g_l[C_], b_l[C_];
    __shared__ float red[2][8][32];
    g_l[threadIdx.x] = gamma[threadIdx.x];
    b_l[threadIdx.x] = beta[threadIdx.x];

    float v[32];
    float s = 0.f, s2 = 0.f;
    #pragma unroll
    for (int j = 0; j < 32; j++) {
        v[j] = xb[(size_t)(k0 + j) * HW_];
        s += v[j]; s2 += v[j] * v[j];
    }
    red[0][kg][lm] = s; red[1][kg][lm] = s2;
    __syncthreads();
    float ts = 0.f, ts2 = 0.f;
    #pragma unroll
    for (int g = 0; g < 8; g++) { ts += red[0][g][lm]; ts2 += red[1][g][lm]; }
    const float mu = ts * (1.f / C_);
    const float var = ts2 * (1.f / C_) - mu * mu;
    const float rstd = rsqrtf(var + EPS_);

    uint4 hv[4];
    unsigned* hp = (unsigned*)hv;
    #pragma unroll
    for (int jp = 0; jp < 16; jp++) {
        float l0 = (v[2*jp]   - mu) * rstd * g_l[k0 + 2*jp]   + b_l[k0 + 2*jp];
        float l1 = (v[2*jp+1] - mu) * rstd * g_l[k0 + 2*jp+1] + b_l[k0 + 2*jp+1];
        hp[jp] = pk2n(l0, l1);
    }
    const int panel = b * (HW_ / 32) + blockIdx.x;
    #pragma unroll
    for (int q = 0; q < 4; q++) {
        const int kk = k0 + 8 * q;
        const int ks = kk >> 4;
        const int hi = (kk >> 3) & 1;
        *(uint4*)(xf + frag_off(panel, ks, lm + 32 * hi)) = hv[q];
    }
}

// ---------------- MFMA QKV GEMM (pure bf16, fragment-linear operands, bf16 out) ----------------
__global__ __launch_bounds__(256) void k_qkv_mfma16(
    const ushort_t* __restrict__ xf, const ushort_t* __restrict__ wf,
    ushort_t* __restrict__ qkv16)
{
    const int b = blockIdx.z;
    const int m0 = blockIdx.x * 128, n0 = blockIdx.y * 128;
    const int tid = threadIdx.x;
    const int lane = tid & 63, wv = tid >> 6;
    const int wr = wv >> 1, wc = wv & 1;
    const int lm = lane & 31;

    const int pa0 = b * (HW_ / 32) + (m0 >> 5) + wr * 2;
    const int pa1 = pa0 + 1;
    const int pb0 = (n0 >> 5) + wc * 2;
    const int pb1 = pb0 + 1;

    f32x16 acc00, acc01, acc10, acc11;
    #pragma unroll
    for (int r = 0; r < 16; r++) { acc00[r] = 0.f; acc01[r] = 0.f; acc10[r] = 0.f; acc11[r] = 0.f; }

    #pragma unroll 8
    for (int ks = 0; ks < 16; ks++) {
        bf16x8 a0 = *(const bf16x8*)(xf + frag_off(pa0, ks, lane));
        bf16x8 a1 = *(const bf16x8*)(xf + frag_off(pa1, ks, lane));
        bf16x8 b0 = *(const bf16x8*)(wf + frag_off(pb0, ks, lane));
        bf16x8 b1 = *(const bf16x8*)(wf + frag_off(pb1, ks, lane));
        acc00 = __builtin_amdgcn_mfma_f32_32x32x16_bf16(b0, a0, acc00, 0, 0, 0);
        acc01 = __builtin_amdgcn_mfma_f32_32x32x16_bf16(b1, a0, acc01, 0, 0, 0);
        acc10 = __builtin_amdgcn_mfma_f32_32x32x16_bf16(b0, a1, acc10, 0, 0, 0);
        acc11 = __builtin_amdgcn_mfma_f32_32x32x16_bf16(b1, a1, acc11, 0, 0, 0);
    }

    const int hv4 = (lane >> 5) * 4;
    #define STORE_ACC(ACC, MT, NT) { \
        ushort_t* o = qkv16 + ((size_t)b * HW_ + m0 + wr * 64 + (MT) * 32 + lm) * 768 \
                    + n0 + wc * 64 + (NT) * 32 + hv4; \
        _Pragma("unroll") \
        for (int g = 0; g < 4; g++) { \
            uint2 pr; \
            pr.x = pk2n(ACC[4*g + 0], ACC[4*g + 1]); \
            pr.y = pk2n(ACC[4*g + 2], ACC[4*g + 3]); \
            *(uint2*)(o + 8 * g) = pr; } }
    STORE_ACC(acc00, 0, 0)
    STORE_ACC(acc01, 0, 1)
    STORE_ACC(acc10, 1, 0)
    STORE_ACC(acc11, 1, 1)
    #undef STORE_ACC
}

// ---------------- fused LN + QKV GEMM (fp32, fallback tiers) ----------------
#define GBM 128
#define GBN 128
#define GBK 8
__global__ __launch_bounds__(256) void k_qkv_gemm(
    const float* __restrict__ x, const float* __restrict__ mu_rstd,
    const float* __restrict__ gamma, const float* __restrict__ beta,
    const float* __restrict__ wq, const float* __restrict__ wk, const float* __restrict__ wv,
    float* __restrict__ qkv)
{
    const int b  = blockIdx.z;
    const int m0 = blockIdx.x * GBM;
    const int n0 = blockIdx.y * GBN;
    __shared__ float a_l[GBK][GBM + 4];
    __shared__ float b_l[GBK][GBN + 4];
    __shared__ float g_l[C_], bt_l[C_];
    const int tid = threadIdx.x;
    g_l[tid] = gamma[tid];
    bt_l[tid] = beta[tid];

    const int mm = tid & 127;
    const int kg = tid >> 7;
    const int nn = tid >> 1;
    const int kq = (tid & 1) * 4;
    const float2 mr = ((const float2*)mu_rstd)[b * HW_ + m0 + mm];
    const float* xbase = x + (size_t)b * C_ * HW_ + m0 + mm;
    const int n = n0 + nn;
    const float* wrow = (n < 256) ? (wq + (size_t)n * C_)
                     : (n < 512) ? (wk + (size_t)(n - 256) * C_)
                                 : (wv + (size_t)(n - 512) * C_);
    float acc[8][8] = {};
    const int tx = tid & 15, ty = tid >> 4;

    for (int kt = 0; kt < C_; kt += GBK) {
        __syncthreads();
        #pragma unroll
        for (int j = 0; j < 4; j++) {
            int kk = kg + j * 2;
            int c = kt + kk;
            float xv = xbase[(size_t)c * HW_];
            a_l[kk][mm] = (xv - mr.x) * mr.y * g_l[c] + bt_l[c];
        }
        float4 w4 = *(const float4*)(wrow + kt + kq);
        b_l[kq + 0][nn] = w4.x; b_l[kq + 1][nn] = w4.y;
        b_l[kq + 2][nn] = w4.z; b_l[kq + 3][nn] = w4.w;
        __syncthreads();
        #pragma unroll
        for (int kk = 0; kk < GBK; kk++) {
            float4 a0 = *(const float4*)&a_l[kk][ty * 8];
            float4 a1 = *(const float4*)&a_l[kk][ty * 8 + 4];
            float4 b0 = *(const float4*)&b_l[kk][tx * 8];
            float4 b1 = *(const float4*)&b_l[kk][tx * 8 + 4];
            float av[8] = {a0.x,a0.y,a0.z,a0.w,a1.x,a1.y,a1.z,a1.w};
            float bv[8] = {b0.x,b0.y,b0.z,b0.w,b1.x,b1.y,b1.z,b1.w};
            #pragma unroll
            for (int i = 0; i < 8; i++)
                #pragma unroll
                for (int jj = 0; jj < 8; jj++)
                    acc[i][jj] += av[i] * bv[jj];
        }
    }
    float* out0 = qkv + ((size_t)b * HW_ + m0 + ty * 8) * 768 + n0 + tx * 8;
    #pragma unroll
    for (int i = 0; i < 8; i++) {
        *(float4*)(out0 + (size_t)i * 768)     = make_float4(acc[i][0], acc[i][1], acc[i][2], acc[i][3]);
        *(float4*)(out0 + (size_t)i * 768 + 4) = make_float4(acc[i][4], acc[i][5], acc[i][6], acc[i][7]);
    }
}

// ---------------- exact top-128: radix-256, 8 waves, bank-staggered histograms ----------------
__device__ __forceinline__ unsigned fkeyu(unsigned u)
{
    return (u & 0x80000000u) ? ~u : (u | 0x80000000u);
}
__device__ __forceinline__ unsigned ifkey(unsigned k)
{
    return (k & 0x80000000u) ? (k ^ 0x80000000u) : ~k;
}

__global__ __launch_bounds__(512) void k_topk(const unsigned* __restrict__ aff,
                                              int* __restrict__ idxo, float* __restrict__ simso)
{
    const int row = blockIdx.x;
    const int tid = threadIdx.x;
    const int lane = tid & 63, wid = tid >> 6;       // 8 waves
    __shared__ __align__(16) unsigned key_l[HW_];    // 64 KB
    __shared__ unsigned hist[8][257];                // stride 257 => same bin spans 8 banks
    __shared__ unsigned sh_prefix;
    __shared__ int sh_need;
    __shared__ int partG[8], partE[8];

    // stage fkeys once (coalesced uint4)
    const uint4* a4 = (const uint4*)(aff + (size_t)row * HW_);
    #pragma unroll 8
    for (int j = 0; j < 8; j++) {
        int i4 = j * 512 + tid;
        uint4 v = a4[i4];
        key_l[4 * i4 + 0] = fkeyu(v.x);
        key_l[4 * i4 + 1] = fkeyu(v.y);
        key_l[4 * i4 + 2] = fkeyu(v.z);
        key_l[4 * i4 + 3] = fkeyu(v.w);
    }
    for (int i = tid; i < 8 * 257; i += 512) ((unsigned*)hist)[i] = 0u;
    if (tid == 0) { sh_prefix = 0u; sh_need = TOPK_; }
    __syncthreads();

    const int qbase = wid * 2048;                    // each wave owns 2048 keys

    // pass-0 histogram (full array, top 8 bits), per-wave sub-histogram
    #pragma unroll 8
    for (int j = 0; j < 8; j++) {
        uint4 k4 = *(const uint4*)&key_l[qbase + j * 256 + lane * 4];
        #pragma unroll
        for (int e = 0; e < 4; e++)
            atomicAdd(&hist[wid][((const unsigned*)&k4)[e] >> 24], 1u);
    }
    __syncthreads();

    for (int pass = 0; pass < 4; pass++) {
        if (wid == 0) {
            const unsigned pref = sh_prefix;
            const unsigned need = (unsigned)sh_need;
            unsigned c[4]; unsigned loc = 0;
            #pragma unroll
            for (int i = 0; i < 4; i++) {
                unsigned t = 0;
                #pragma unroll
                for (int hh = 0; hh < 8; hh++) t += hist[hh][lane*4+i];
                c[i] = t;
                loc += t;
            }
            unsigned s = loc;
            #pragma unroll
            for (int off = 1; off < 64; off <<= 1) {
                unsigned t = (unsigned)__shfl_down((int)s, off);
                if (lane + off < 64) s += t;
            }
            unsigned run = s - loc;
            #pragma unroll
            for (int i = 3; i >= 0; i--) {
                unsigned incl = run + c[i];
                if (incl >= need && run < need) {
                    sh_prefix = (pref << 8) | (unsigned)(lane * 4 + i);
                    sh_need = (int)(need - run);
                }
                run = incl;
            }
        }
        __syncthreads();
        if (pass == 3) break;

        const unsigned prefT = sh_prefix;
        const int shift = 24 - 8 * pass;
        for (int i = tid; i < 8 * 257; i += 512) ((unsigned*)hist)[i] = 0u;
        __syncthreads();
        const int nshift = shift - 8;
        #pragma unroll 8
        for (int j = 0; j < 8; j++) {
            uint4 k4 = *(const uint4*)&key_l[qbase + j * 256 + lane * 4];
            #pragma unroll
            for (int e = 0; e < 4; e++) {
                unsigned key = ((const unsigned*)&k4)[e];
                if ((key >> shift) == prefT)
                    atomicAdd(&hist[wid][(key >> nshift) & 255u], 1u);
            }
        }
        __syncthreads();
    }

    const unsigned T = sh_prefix;
    const int e_take = sh_need;

    int cg = 0, ce = 0;
    #pragma unroll 8
    for (int j = 0; j < 8; j++) {
        uint4 k4 = *(const uint4*)&key_l[qbase + j * 256 + lane * 4];
        #pragma unroll
        for (int e = 0; e < 4; e++) {
            unsigned key = ((const unsigned*)&k4)[e];
            cg += (key > T);
            ce += (key == T);
        }
    }
    #pragma unroll
    for (int o = 32; o >= 1; o >>= 1) { cg += __shfl_xor(cg, o); ce += __shfl_xor(ce, o); }
    if (lane == 0) { partG[wid] = cg; partE[wid] = ce; }
    __syncthreads();

    int gpre = 0, epre = 0;
    for (int q = 0; q < wid; q++) { gpre += partG[q]; epre += partE[q]; }
    int base = gpre + ((epre < e_take) ? epre : e_take);
    int rem_eq = e_take - epre;
    if (rem_eq < 0) rem_eq = 0;
    if (rem_eq > ce) rem_eq = ce;

    int* orow = idxo + (size_t)row * TOPK_;
    float* srow = simso + (size_t)row * TOPK_;
    const unsigned long long ltm = (1ULL << lane) - 1ULL;

    for (int j = 0; j < 32; j++) {
        const int i = qbase + j * 64 + lane;
        const unsigned key = key_l[i];
        const bool gt = key > T;
        const bool eq = (key == T);
        const unsigned long long bg = __ballot(gt);
        const unsigned long long be = __ballot(eq);
        const int cgc = __popcll(bg);
        const int cec = __popcll(be);
        if (gt) {
            int slot = base + __popcll(bg & ltm);
            orow[slot] = i; srow[slot] = __uint_as_float(ifkey(key));
        }
        if (eq && rem_eq > 0) {
            int r = __popcll(be & ltm);
            if (r < rem_eq) {
                int slot = base + cgc + r;
                orow[slot] = i; srow[slot] = __uint_as_float(ifkey(key));
            }
        }
        const int etk = (cec < rem_eq) ? cec : rem_eq;
        base += cgc + etk;
        rem_eq -= etk;
    }
}

// ---------------- CSR inverse-index construction ----------------
__global__ __launch_bounds__(128) void k_count(const int* __restrict__ idxb, int* __restrict__ cnt)
{
    const int sp = blockIdx.x, b = blockIdx.y;
    int pix = idxb[(b * NSP_ + sp) * TOPK_ + threadIdx.x];
    atomicAdd(&cnt[b * HW_ + pix], 1);
}

__global__ __launch_bounds__(1024) void k_scan(const int* __restrict__ cnt, int* __restrict__ offs)
{
    const int b = blockIdx.x;
    const int tid = threadIdx.x;
    __shared__ int sc[1024];
    const int base = b * HW_;
    int loc[16];
    int s = 0;
    #pragma unroll
    for (int i = 0; i < 16; i++) {
        int c = cnt[base + tid * 16 + i];
        loc[i] = s;
        s += c;
    }
    sc[tid] = s;
    __syncthreads();
    for (int off = 1; off < 1024; off <<= 1) {
        int add = (tid >= off) ? sc[tid - off] : 0;
        __syncthreads();
        sc[tid] += add;
        __syncthreads();
    }
    int excl = sc[tid] - s;
    #pragma unroll
    for (int i = 0; i < 16; i++)
        offs[base + tid * 16 + i] = excl + loc[i];
}

// fill: compute each slot's DESTINATION position in CSR order (dpos), global row id
__global__ __launch_bounds__(128) void k_fill(const int* __restrict__ idxb, const int* __restrict__ offs,
                                              int* __restrict__ cursor, int* __restrict__ dpos)
{
    const int sp = blockIdx.x, b = blockIdx.y;
    const int slot = threadIdx.x;
    const int gid = (b * NSP_ + sp) * TOPK_ + slot;
    int pix = idxb[gid];
    int pos = atomicAdd(&cursor[b * HW_ + pix], 1);
    dpos[gid] = b * (NSP_ * TOPK_) + offs[b * HW_ + pix] + pos;
}

// ---------------- MFMA attention, bf16 qkv (tier 1) ----------------
__global__ __launch_bounds__(256, 4) void k_attn16(
    const ushort_t* __restrict__ qkv16, const int* __restrict__ idxb,
    const int* __restrict__ dpos, const float* __restrict__ sims,
    ushort_t* __restrict__ O16)
{
    const int sp = blockIdx.x, h = blockIdx.y, b = blockIdx.z;
    __shared__ int idx_l[TOPK_];
    __shared__ int dp_l[TOPK_];
    __shared__ float sims_l[TOPK_];
    __shared__ __align__(16) ushort_t vt[HD_][TOPK_ + 8];
    __shared__ __align__(16) ushort_t k_l[TOPK_][40];   // 80B stride, 16B aligned

    const int tid = threadIdx.x;
    const int roff = (b * NSP_ + sp) * TOPK_;
    if (tid < TOPK_) {
        idx_l[tid] = idxb[roff + tid];
        dp_l[tid] = dpos[roff + tid];
        sims_l[tid] = sims[roff + tid];
    }
    __syncthreads();

    const ushort_t* qb = qkv16 + (size_t)b * HW_ * 768;

    // stage sims-weighted V^T into LDS (bf16, native pair converts)
    {
        const int s = tid >> 1, ch = (tid & 1) * 16;
        const float wgt = sims_l[s];
        const ushort_t* vrow = qb + (size_t)idx_l[s] * 768 + 512 + h * HD_ + ch;
        bf16x8 v0 = *(const bf16x8*)(vrow);
        bf16x8 v1 = *(const bf16x8*)(vrow + 8);
        #pragma unroll
        for (int jp = 0; jp < 4; jp++) {
            unsigned p0 = pk2n(bf2f((ushort_t)v0[2*jp]) * wgt, bf2f((ushort_t)v0[2*jp+1]) * wgt);
            vt[ch + 2*jp][s]     = (ushort_t)p0;
            vt[ch + 2*jp + 1][s] = (ushort_t)(p0 >> 16);
            unsigned p1 = pk2n(bf2f((ushort_t)v1[2*jp]) * wgt, bf2f((ushort_t)v1[2*jp+1]) * wgt);
            vt[ch + 8 + 2*jp][s]     = (ushort_t)p1;
            vt[ch + 8 + 2*jp + 1][s] = (ushort_t)(p1 >> 16);
        }
    }

    // stage K rows into LDS once (shared by all 4 waves); one 64B line per row
    {
        const int row = tid >> 1, half = tid & 1;
        const ushort_t* kp = qb + (size_t)idx_l[row] * 768 + 256 + h * HD_ + half * 16;
        uint4 c0 = *(const uint4*)(kp);
        uint4 c1 = *(const uint4*)(kp + 8);
        *(uint4*)&k_l[row][half * 16]     = c0;
        *(uint4*)&k_l[row][half * 16 + 8] = c1;
    }
    __syncthreads();   // vt and k_l ready

    const int lane = tid & 63, w = tid >> 6;
    const int lq = lane & 31, hi = lane >> 5;
    const int qrow = idx_l[w * 32 + lq];

    f32x16 sacc[4];
    #pragma unroll
    for (int s = 0; s < 4; s++)
        #pragma unroll
        for (int r = 0; r < 16; r++) sacc[s][r] = 0.f;

    // QK^T: A = K rows (LDS), B = Q^T cols (global, per-wave unique)
    #pragma unroll
    for (int t = 0; t < 2; t++) {
        bf16x8 qf = *(const bf16x8*)(qb + (size_t)qrow * 768 + h * HD_ + t * 16 + hi * 8);
        #pragma unroll
        for (int s = 0; s < 4; s++) {
            bf16x8 kf = *(const bf16x8*)&k_l[s * 32 + lq][t * 16 + hi * 8];
            sacc[s] = __builtin_amdgcn_mfma_f32_32x32x16_bf16(kf, qf, sacc[s], 0, 0, 0);
        }
    }

    // full softmax over s (lane holds 64 of 128; partner in lane^32)
    float m = fmaxf(sacc[0][0], sacc[0][1]);
    #pragma unroll
    for (int s = 0; s < 4; s++)
        #pragma unroll
        for (int r = (s == 0 ? 2 : 0); r < 16; r += 2)
            m = fmaxf(m, fmaxf(sacc[s][r], sacc[s][r + 1]));
    m = fmaxf(m, __shfl_xor(m, 32));
    const float mb = -m * SC2_F;                    // exp2 prescale
    float l0 = 0.f, l1 = 0.f;
    #pragma unroll
    for (int s = 0; s < 4; s++)
        #pragma unroll
        for (int r = 0; r < 16; r += 2) {
            float p0 = exp2f(fmaf(sacc[s][r],     SC2_F, mb));
            float p1 = exp2f(fmaf(sacc[s][r + 1], SC2_F, mb));
            sacc[s][r] = p0;
            sacc[s][r + 1] = p1;
            l0 += p0;
            l1 += p1;
        }
    float lsum = l0 + l1;
    lsum += __shfl_xor(lsum, 32);

    f32x16 oacc;
    #pragma unroll
    for (int r = 0; r < 16; r++) oacc[r] = 0.f;

    #pragma unroll
    for (int t = 0; t < 8; t++) {
        const int st = t >> 1, rb = (t & 1) * 8;
        unsigned A0 = pk2n(sacc[st][rb + 0], sacc[st][rb + 1]);
        unsigned A1 = pk2n(sacc[st][rb + 2], sacc[st][rb + 3]);
        unsigned B0 = pk2n(sacc[st][rb + 4], sacc[st][rb + 5]);
        unsigned B1 = pk2n(sacc[st][rb + 6], sacc[st][rb + 7]);
        FragU pf;
        half_swap(A0, B0, pf.u[0], pf.u[2], hi);
        half_swap(A1, B1, pf.u[1], pf.u[3], hi);
        bf16x8 vf = *(const bf16x8*)&vt[lq][t * 16 + hi * 8];
        oacc = __builtin_amdgcn_mfma_f32_32x32x16_bf16(vf, pf.v, oacc, 0, 0, 0);
    }

    const float wt = sims_l[w * 32 + lq] / lsum;
    ushort_t* orow = O16 + (size_t)dp_l[w * 32 + lq] * C_ + h * HD_ + 4 * hi;
    #pragma unroll
    for (int g = 0; g < 4; g++) {
        uint2 pr;
        pr.x = pk2n(oacc[4*g + 0] * wt, oacc[4*g + 1] * wt);
        pr.y = pk2n(oacc[4*g + 2] * wt, oacc[4*g + 3] * wt);
        *(uint2*)(orow + 8 * g) = pr;
    }
}

// ---------------- MFMA attention, fp32 qkv (fallback tiers) ----------------
template <bool DENSE>
__global__ __launch_bounds__(256) void k_attn_mfma(
    const float* __restrict__ qkv, const int* __restrict__ idxb,
    const int* __restrict__ dpos, const float* __restrict__ sims,
    ushort_t* __restrict__ O16, float* __restrict__ tmp)
{
    const int sp = blockIdx.x, h = blockIdx.y, b = blockIdx.z;
    __shared__ int idx_l[TOPK_];
    __shared__ int dp_l[TOPK_];
    __shared__ float sims_l[TOPK_];
    __shared__ __align__(16) ushort_t vt[HD_][TOPK_ + 8];

    const int tid = threadIdx.x;
    const int roff = (b * NSP_ + sp) * TOPK_;
    if (tid < TOPK_) {
        idx_l[tid] = idxb[roff + tid];
        sims_l[tid] = sims[roff + tid];
        if (DENSE) dp_l[tid] = dpos[roff + tid];
    }
    __syncthreads();

    const float* qb = qkv + (size_t)b * HW_ * 768;

    {
        const int s = tid >> 1, ch = (tid & 1) * 16;
        const float wgt = sims_l[s];
        const float* vrow = qb + (size_t)idx_l[s] * 768 + 512 + h * HD_ + ch;
        #pragma unroll
        for (int j4 = 0; j4 < 4; j4++) {
            float4 vv = *(const float4*)(vrow + j4 * 4);
            vt[ch + j4 * 4 + 0][s] = f2bf(vv.x * wgt);
            vt[ch + j4 * 4 + 1][s] = f2bf(vv.y * wgt);
            vt[ch + j4 * 4 + 2][s] = f2bf(vv.z * wgt);
            vt[ch + j4 * 4 + 3][s] = f2bf(vv.w * wgt);
        }
    }

    const int lane = tid & 63, w = tid >> 6;
    const int lq = lane & 31, hi = lane >> 5;
    const int qrow = idx_l[w * 32 + lq];

    f32x16 sacc[4];
    #pragma unroll
    for (int s = 0; s < 4; s++)
        #pragma unroll
        for (int r = 0; r < 16; r++) sacc[s][r] = 0.f;

    #pragma unroll
    for (int t = 0; t < 2; t++) {
        const float* qp = qb + (size_t)qrow * 768 + h * HD_ + t * 16 + hi * 8;
        float q8[8];
        {
            float4 t0 = *(const float4*)qp;
            float4 t1 = *(const float4*)(qp + 4);
            q8[0]=t0.x; q8[1]=t0.y; q8[2]=t0.z; q8[3]=t0.w;
            q8[4]=t1.x; q8[5]=t1.y; q8[6]=t1.z; q8[7]=t1.w;
        }
        FragU qh, ql; split8(q8, qh, ql);
        #pragma unroll
        for (int s = 0; s < 4; s++) {
            const int krow = idx_l[s * 32 + lq];
            const float* kp = qb + (size_t)krow * 768 + 256 + h * HD_ + t * 16 + hi * 8;
            float k8[8];
            {
                float4 t0 = *(const float4*)kp;
                float4 t1 = *(const float4*)(kp + 4);
                k8[0]=t0.x; k8[1]=t0.y; k8[2]=t0.z; k8[3]=t0.w;
                k8[4]=t1.x; k8[5]=t1.y; k8[6]=t1.z; k8[7]=t1.w;
            }
            FragU kh, kl; split8(k8, kh, kl);
            sacc[s] = __builtin_amdgcn_mfma_f32_32x32x16_bf16(kh.v, qh.v, sacc[s], 0, 0, 0);
            sacc[s] = __builtin_amdgcn_mfma_f32_32x32x16_bf16(kh.v, ql.v, sacc[s], 0, 0, 0);
            sacc[s] = __builtin_amdgcn_mfma_f32_32x32x16_bf16(kl.v, qh.v, sacc[s], 0, 0, 0);
        }
    }

    float m = -1e30f;
    #pragma unroll
    for (int s = 0; s < 4; s++)
        #pragma unroll
        for (int r = 0; r < 16; r++) m = fmaxf(m, sacc[s][r]);
    m = fmaxf(m, __shfl_xor(m, 32));
    float lsum = 0.f;
    #pragma unroll
    for (int s = 0; s < 4; s++)
        #pragma unroll
        for (int r = 0; r < 16; r++) {
            float p = __expf((sacc[s][r] - m) * SCALE_F);
            sacc[s][r] = p;
            lsum += p;
        }
    lsum += __shfl_xor(lsum, 32);

    __syncthreads();

    f32x16 oacc;
    #pragma unroll
    for (int r = 0; r < 16; r++) oacc[r] = 0.f;

    #pragma unroll
    for (int t = 0; t < 8; t++) {
        const int st = t >> 1, rb = (t & 1) * 8;
        unsigned A0 = pk2(sacc[st][rb + 0], sacc[st][rb + 1]);
        unsigned A1 = pk2(sacc[st][rb + 2], sacc[st][rb + 3]);
        unsigned B0 = pk2(sacc[st][rb + 4], sacc[st][rb + 5]);
        unsigned B1 = pk2(sacc[st][rb + 6], sacc[st][rb + 7]);
        unsigned sA0 = (unsigned)__shfl_xor((int)A0, 32);
        unsigned sA1 = (unsigned)__shfl_xor((int)A1, 32);
        unsigned sB0 = (unsigned)__shfl_xor((int)B0, 32);
        unsigned sB1 = (unsigned)__shfl_xor((int)B1, 32);
        FragU pf;
        pf.u[0] = hi ? sB0 : A0;
        pf.u[1] = hi ? sB1 : A1;
        pf.u[2] = hi ? B0 : sA0;
        pf.u[3] = hi ? B1 : sA1;
        bf16x8 vf = *(const bf16x8*)&vt[lq][t * 16 + hi * 8];
        oacc = __builtin_amdgcn_mfma_f32_32x32x16_bf16(vf, pf.v, oacc, 0, 0, 0);
    }

    const float wt = sims_l[w * 32 + lq] / lsum;
    if (DENSE) {
        ushort_t* orow = O16 + (size_t)dp_l[w * 32 + lq] * C_ + h * HD_ + 4 * hi;
        #pragma unroll
        for (int g = 0; g < 4; g++) {
            uint2 pr;
            pr.x = pk2(oacc[4*g + 0] * wt, oacc[4*g + 1] * wt);
            pr.y = pk2(oacc[4*g + 2] * wt, oacc[4*g + 3] * wt);
            *(uint2*)(orow + 8 * g) = pr;
        }
    } else {
        float* drow = tmp + ((size_t)(b * HW_) + qrow) * C_ + h * HD_;
        #pragma unroll
        for (int r = 0; r < 16; r++) {
            int c = (r & 3) + 8 * (r >> 2) + 4 * hi;
            atomicAdd(&drow[c], oacc[r] * wt);
        }
    }
}

// ---------------- fallback attention (strided atomics straight to out) ----------------
__global__ __launch_bounds__(128) void k_attn_fb(
    const float* __restrict__ qkv, const int* __restrict__ idxb,
    const float* __restrict__ sims, float* __restrict__ dst)
{
    const int sp = blockIdx.x, h = blockIdx.y, b = blockIdx.z;
    __shared__ float k_lf[TOPK_][HD_];
    __shared__ float vw_l[TOPK_][HD_];
    __shared__ float sims_l[TOPK_];
    __shared__ int idx_l[TOPK_];
    const int tid = threadIdx.x;
    const int roff = (b * NSP_ + sp) * TOPK_;
    idx_l[tid] = idxb[roff + tid];
    sims_l[tid] = sims[roff + tid];
    __syncthreads();
    const float* base = qkv + (size_t)b * HW_ * 768;
    #pragma unroll
    for (int it = 0; it < 8; it++) {
        int flat = it * 128 + tid;
        int s = flat >> 3, c4 = (flat & 7) * 4;
        const float* krow = base + (size_t)idx_l[s] * 768 + 256 + h * HD_ + c4;
        *(float4*)&k_lf[s][c4] = *(const float4*)krow;
        const float* vrow = base + (size_t)idx_l[s] * 768 + 512 + h * HD_ + c4;
        float4 vv = *(const float4*)vrow;
        float wgt = sims_l[s];
        *(float4*)&vw_l[s][c4] = make_float4(vv.x * wgt, vv.y * wgt, vv.z * wgt, vv.w * wgt);
    }
    float q[HD_];
    const int pix = idx_l[tid];
    const float* qrow = base + (size_t)pix * 768 + h * HD_;
    #pragma unroll
    for (int j = 0; j < 8; j++) {
        float4 t4 = *(const float4*)(qrow + j * 4);
        q[j*4] = t4.x; q[j*4+1] = t4.y; q[j*4+2] = t4.z; q[j*4+3] = t4.w;
    }
    __syncthreads();
    float m = -1e30f, l = 0.f, acc[HD_];
    #pragma unroll
    for (int c = 0; c < HD_; c++) acc[c] = 0.f;
    for (int s = 0; s < TOPK_; s++) {
        float d = 0.f;
        #pragma unroll
        for (int c4 = 0; c4 < 8; c4++) {
            float4 kk4 = *(const float4*)&k_lf[s][c4 * 4];
            d += q[c4*4]*kk4.x + q[c4*4+1]*kk4.y + q[c4*4+2]*kk4.z + q[c4*4+3]*kk4.w;
        }
        d *= SCALE_F;
        float mn = fmaxf(m, d);
        float fac = __expf(m - mn);
        float p = __expf(d - mn);
        l = l * fac + p;
        #pragma unroll
        for (int c4 = 0; c4 < 8; c4++) {
            float4 vv4 = *(const float4*)&vw_l[s][c4 * 4];
            acc[c4*4]   = acc[c4*4]   * fac + p * vv4.x;
            acc[c4*4+1] = acc[c4*4+1] * fac + p * vv4.y;
            acc[c4*4+2] = acc[c4*4+2] * fac + p * vv4.z;
            acc[c4*4+3] = acc[c4*4+3] * fac + p * vv4.w;
        }
        m = mn;
    }
    const float wt = sims_l[tid] / l;
    float* dbase = dst + ((size_t)b * C_ + h * HD_) * HW_ + pix;
    #pragma unroll
    for (int c = 0; c < HD_; c++) atomicAdd(dbase + (size_t)c * HW_, acc[c] * wt);
}

// ---------------- final (CSR gather, bf16 qkv, CONTIGUOUS rows) ----------------
__global__ __launch_bounds__(256) void k_final216(
    const ushort_t* __restrict__ qkv16, const ushort_t* __restrict__ O16,
    const int* __restrict__ cnt, const int* __restrict__ offs,
    float* __restrict__ out)
{
    const int b = blockIdx.z;
    const int p0 = blockIdx.x * 64, c0 = blockIdx.y * 64;
    __shared__ float t[64][65];
    const int tid = threadIdx.x;
    const int cc = tid & 63;
    #pragma unroll
    for (int it = 0; it < 16; it++) {
        int r = it * 4 + (tid >> 6);
        int p = p0 + r;
        float val = bf2f(qkv16[((size_t)b * HW_ + p) * 768 + 512 + c0 + cc]);
        int n = cnt[b * HW_ + p];
        const ushort_t* ob = O16 + ((size_t)b * (NSP_ * TOPK_) + offs[b * HW_ + p]) * C_ + c0 + cc;
        for (int j = 0; j < n; j++)
            val += bf2f(ob[(size_t)j * C_]);
        t[r][cc] = val;
    }
    __syncthreads();
    #pragma unroll
    for (int it = 0; it < 16; it++) {
        int flat = it * 256 + tid;
        int rr = flat >> 6, pp = flat & 63;
        out[((size_t)b * C_ + c0 + rr) * HW_ + p0 + pp] = t[pp][rr];
    }
}

// ---------------- final (CSR gather, fp32 qkv — tier 2, CONTIGUOUS rows) ----------------
__global__ __launch_bounds__(256) void k_final2(
    const float* __restrict__ qkv, const ushort_t* __restrict__ O16,
    const int* __restrict__ cnt, const int* __restrict__ offs,
    float* __restrict__ out)
{
    const int b = blockIdx.z;
    const int p0 = blockIdx.x * 64, c0 = blockIdx.y * 64;
    __shared__ float t[64][65];
    const int tid = threadIdx.x;
    const int cc = tid & 63;
    #pragma unroll
    for (int it = 0; it < 16; it++) {
        int r = it * 4 + (tid >> 6);
        int p = p0 + r;
        float val = qkv[((size_t)b * HW_ + p) * 768 + 512 + c0 + cc];
        int n = cnt[b * HW_ + p];
        const ushort_t* ob = O16 + ((size_t)b * (NSP_ * TOPK_) + offs[b * HW_ + p]) * C_ + c0 + cc;
        for (int j = 0; j < n; j++)
            val += bf2f(ob[(size_t)j * C_]);
        t[r][cc] = val;
    }
    __syncthreads();
    #pragma unroll
    for (int it = 0; it < 16; it++) {
        int flat = it * 256 + tid;
        int rr = flat >> 6, pp = flat & 63;
        out[((size_t)b * C_ + c0 + rr) * HW_ + p0 + pp] = t[pp][rr];
    }
}

// ---------------- final (tmp variant) ----------------
__global__ __launch_bounds__(256) void k_final(const float* __restrict__ qkv,
                                               const float* __restrict__ tmp, float* __restrict__ out)
{
    const int b = blockIdx.z;
    const int p0 = blockIdx.x * 64, c0 = blockIdx.y * 64;
    __shared__ float t[64][65];
    const int tid = threadIdx.x;
    #pragma unroll
    for (int it = 0; it < 16; it++) {
        int flat = it * 256 + tid;
        int r = flat >> 6, cc2 = flat & 63;
        float v = qkv[((size_t)b * HW_ + p0 + r) * 768 + 512 + c0 + cc2]
                + tmp[((size_t)b * HW_ + p0 + r) * C_ + c0 + cc2];
        t[r][cc2] = v;
    }
    __syncthreads();
    #pragma unroll
    for (int it = 0; it < 16; it++) {
        int flat = it * 256 + tid;
        int rr = flat >> 6, pp = flat & 63;
        out[((size_t)b * C_ + c0 + rr) * HW_ + p0 + pp] = t[pp][rr];
    }
}

__global__ __launch_bounds__(256) void k_vinit(const float* __restrict__ qkv, float* __restrict__ out)
{
    const int b = blockIdx.z;
    const int p0 = blockIdx.x * 64, c0 = blockIdx.y * 64;
    __shared__ float t[64][65];
    const int tid = threadIdx.x;
    #pragma unroll
    for (int it = 0; it < 16; it++) {
        int flat = it * 256 + tid;
        int r = flat >> 6, cc2 = flat & 63;
        t[r][cc2] = qkv[((size_t)b * HW_ + p0 + r) * 768 + 512 + c0 + cc2];
    }
    __syncthreads();
    #pragma unroll
    for (int it = 0; it < 16; it++) {
        int flat = it * 256 + tid;
        int rr = flat >> 6, pp = flat & 63;
        out[((size_t)b * C_ + c0 + rr) * HW_ + p0 + pp] = t[pp][rr];
    }
}

extern "C" void kernel_launch(void* const* d_in, const int* in_sizes, int n_in,
                              void* d_out, int out_size, void* d_ws, size_t ws_size,
                              hipStream_t stream)
{
    (void)in_sizes; (void)n_in; (void)out_size;
    const float* x     = (const float*)d_in[0];
    const float* aff   = (const float*)d_in[1];
    const float* gamma = (const float*)d_in[2];
    const float* beta  = (const float*)d_in[3];
    const float* wq    = (const float*)d_in[4];
    const float* wk    = (const float*)d_in[5];
    const float* wv    = (const float*)d_in[6];
    float* out = (float*)d_out;
    float* ws  = (float*)d_ws;

    const size_t n_mu   = (size_t)2 * B_ * HW_;
    const size_t n_qkv  = (size_t)B_ * HW_ * 768;
    const size_t n_idx  = (size_t)B_ * NSP_ * TOPK_;
    const size_t n_o16  = (size_t)B_ * NSP_ * TOPK_ * C_ / 2;
    const size_t n_pix  = (size_t)B_ * HW_;
    const size_t n_w2f  = (size_t)768 * C_;
    const size_t n_tmp  = (size_t)B_ * HW_ * C_;

    float*    mu_rstd = ws;
    float*    qkv     = ws + n_mu;
    ushort_t* qkv16   = (ushort_t*)(ws + n_mu);
    int*      idxb    = (int*)(ws + n_mu + n_qkv);
    float*    sims    = ws + n_mu + n_qkv + n_idx;
    float*    big     = ws + n_mu + n_qkv + 2 * n_idx;
    ushort_t* O16     = (ushort_t*)big;
    ushort_t* xf      = (ushort_t*)big;
    int*      cnt     = (int*)(big + n_o16);
    int*      offs    = cnt + n_pix;
    int*      cursor  = offs + n_pix;
    int*      dpos    = cursor + n_pix;
    ushort_t* wf      = (ushort_t*)(dpos + n_idx);

    const size_t need_t1  = (n_mu + n_qkv + 2 * n_idx + n_o16 + 3 * n_pix + n_idx + n_w2f) * 4;
    const size_t need_t2  = (n_mu + n_qkv + 2 * n_idx + n_o16 + 3 * n_pix + n_idx) * 4;
    const size_t need_mid = (n_mu + n_qkv + 2 * n_idx + n_tmp) * 4;

    if (ws_size >= need_t1) {
        k_wsplit16<<<dim3(24), 256, 0, stream>>>(wq, wk, wv, wf);
        k_lnsplit16<<<dim3(HW_ / 32, B_), 256, 0, stream>>>(x, gamma, beta, xf);
        k_qkv_mfma16<<<dim3(HW_ / 128, 768 / 128, B_), 256, 0, stream>>>(xf, wf, qkv16);
        k_topk<<<dim3(B_ * NSP_), 512, 0, stream>>>((const unsigned*)aff, idxb, sims);
        hipMemsetAsync(cnt, 0, 3 * n_pix * 4, stream);
        dim3 gsp(NSP_, B_);
        k_count<<<gsp, 128, 0, stream>>>(idxb, cnt);
        k_scan<<<dim3(B_), 1024, 0, stream>>>(cnt, offs);
        k_fill<<<gsp, 128, 0, stream>>>(idxb, offs, cursor, dpos);
        dim3 ga(NSP_, HEADS_, B_);
        k_attn16<<<ga, 256, 0, stream>>>(qkv16, idxb, dpos, sims, O16);
        dim3 gf(HW_ / 64, C_ / 64, B_);
        k_final216<<<gf, 256, 0, stream>>>(qkv16, O16, cnt, offs, out);
    } else if (ws_size >= need_t2) {
        k_meanvar<<<dim3((B_ * HW_) / 256), 256, 0, stream>>>(x, mu_rstd);
        dim3 gg(HW_ / GBM, 768 / GBN, B_);
        k_qkv_gemm<<<gg, 256, 0, stream>>>(x, mu_rstd, gamma, beta, wq, wk, wv, qkv);
        k_topk<<<dim3(B_ * NSP_), 512, 0, stream>>>((const unsigned*)aff, idxb, sims);
        hipMemsetAsync(cnt, 0, 3 * n_pix * 4, stream);
        dim3 gsp(NSP_, B_);
        k_count<<<gsp, 128, 0, stream>>>(idxb, cnt);
        k_scan<<<dim3(B_), 1024, 0, stream>>>(cnt, offs);
        k_fill<<<gsp, 128, 0, stream>>>(idxb, offs, cursor, dpos);
        dim3 ga(NSP_, HEADS_, B_);
        k_attn_mfma<true><<<ga, 256, 0, stream>>>(qkv, idxb, dpos, sims, O16, nullptr);
        dim3 gf(HW_ / 64, C_ / 64, B_);
        k_final2<<<gf, 256, 0, stream>>>(qkv, O16, cnt, offs, out);
    } else if (ws_size >= need_mid) {
        k_meanvar<<<dim3((B_ * HW_) / 256), 256, 0, stream>>>(x, mu_rstd);
        dim3 gg(HW_ / GBM, 768 / GBN, B_);
        k_qkv_gemm<<<gg, 256, 0, stream>>>(x, mu_rstd, gamma, beta, wq, wk, wv, qkv);
        k_topk<<<dim3(B_ * NSP_), 512, 0, stream>>>((const unsigned*)aff, idxb, sims);
        float* tmp = big;
        hipMemsetAsync(tmp, 0, n_tmp * 4, stream);
        dim3 ga(NSP_, HEADS_, B_);
        k_attn_mfma<false><<<ga, 256, 0, stream>>>(qkv, idxb, nullptr, sims, nullptr, tmp);
        dim3 gf(HW_ / 64, C_ / 64, B_);
        k_final<<<gf, 256, 0, stream>>>(qkv, tmp, out);
    } else {
        k_meanvar<<<dim3((B_ * HW_) / 256), 256, 0, stream>>>(x, mu_rstd);
        dim3 gg(HW_ / GBM, 768 / GBN, B_);
        k_qkv_gemm<<<gg, 256, 0, stream>>>(x, mu_rstd, gamma, beta, wq, wk, wv, qkv);
        k_topk<<<dim3(B_ * NSP_), 512, 0, stream>>>((const unsigned*)aff, idxb, sims);
        dim3 gf(HW_ / 64, C_ / 64, B_);
        k_vinit<<<gf, 256, 0, stream>>>(qkv, out);
        dim3 ga(NSP_, HEADS_, B_);
        k_attn_fb<<<ga, 128, 0, stream>>>(qkv, idxb, sims, out);
    }
}